// Round 19
// baseline (362.849 us; speedup 1.0000x reference)
//
#include <hip/hip_runtime.h>
#include <hip/hip_bf16.h>
#include <cstdint>

typedef unsigned short u16;
typedef u16  u16x8 __attribute__((ext_vector_type(8)));
typedef short s16x8 __attribute__((ext_vector_type(8)));
typedef float f32x4 __attribute__((ext_vector_type(4)));

#define PI_F 3.14159265358979323846f
#define PD(i) ((i) + 3 * ((i) >> 5))

static __device__ __forceinline__ u16 f2bf(float f) {
    union { float f; unsigned u; } v; v.f = f;
    unsigned r = v.u + 0x7fffu + ((v.u >> 16) & 1u);
    return (u16)(r >> 16);
}
static __device__ __forceinline__ float bf2f(u16 h) {
    union { unsigned u; float f; } v; v.u = ((unsigned)h) << 16;
    return v.f;
}

__device__ __forceinline__ void gl_lds16(const u16* g, u16* l) {
    __builtin_amdgcn_global_load_lds(
        (const __attribute__((address_space(1))) unsigned int*)g,
        (__attribute__((address_space(3))) unsigned int*)l, 16, 0, 0);
}

// ---------------------------------------------------------------------------
// Fused prep: cvt (f32->bf16, 3 tensors) + build_E (x6) + tables, one grid.
// ---------------------------------------------------------------------------
__device__ __forceinline__ void cvt_body(int blk, const float* __restrict__ in,
                                         u16* __restrict__ o) {
    int i = blk * 256 + threadIdx.x;
    float4 a = ((const float4*)in)[2 * i];
    float4 b = ((const float4*)in)[2 * i + 1];
    u16x8 vv;
    vv[0] = f2bf(a.x); vv[1] = f2bf(a.y); vv[2] = f2bf(a.z); vv[3] = f2bf(a.w);
    vv[4] = f2bf(b.x); vv[5] = f2bf(b.y); vv[6] = f2bf(b.z); vv[7] = f2bf(b.w);
    ((u16x8*)o)[i] = vv;
}

template<int LOGK>
__device__ __forceinline__ void e3_body(int blk, const float* __restrict__ W,
                                        u16* __restrict__ E) {
    const int K = 1 << LOGK;
    int idx = blk * 256 + threadIdx.x;
    int n = idx >> LOGK, k = idx & (K - 1);
    int o = n >> 2, c = n & 3, i = k >> 2, cp = k & 3;
    const int   qm[4][4] = {{0,1,2,3},{1,0,3,2},{2,3,0,1},{3,2,1,0}};
    const float qs[4][4] = {{1.f,-1.f,-1.f,-1.f},{1.f,1.f,1.f,-1.f},
                            {1.f,-1.f,1.f,1.f},{1.f,1.f,-1.f,1.f}};
    int in_q = K >> 2;
    float w = W[(size_t)qm[c][cp] * 512 * in_q + (size_t)o * in_q + i] * qs[c][cp];
    E[idx] = f2bf(w);
}

// r8 twiddle tables: h=4 @0 (4) | h=32 @4 (32) | h=256 @36 (256) -> 292.
__device__ __forceinline__ void tabs_body(int blk, float2* __restrict__ gws,
                                          float* __restrict__ ph) {
    int i = blk * 256 + threadIdx.x;
    if (i < 292) {
        int off, denom;
        if (i < 4)       { off = 0;  denom = 16;   }
        else if (i < 36) { off = 4;  denom = 128;  }
        else             { off = 36; denom = 1024; }
        float a = (-PI_F) * (float)(i - off) / (float)denom;
        gws[i] = make_float2(cosf(a), sinf(a));
    }
    if (i <= 1024) {
        ph[i] = atanf(logf((float)i * (1.0f / 2048.0f) + 1e-6f));
    }
}

__global__ __launch_bounds__(256) void fat_prep(
        const float* __restrict__ query, const float* __restrict__ key,
        const float* __restrict__ value, u16* __restrict__ Acvt,
        const float* __restrict__ Wq, const float* __restrict__ Wk,
        const float* __restrict__ Wv, u16* __restrict__ Eq,
        u16* __restrict__ Ek, u16* __restrict__ Ev,
        const float* __restrict__ Wint, const float* __restrict__ Wfin,
        const float* __restrict__ Wout, u16* __restrict__ Eint,
        u16* __restrict__ Efin, u16* __restrict__ Eout,
        float2* __restrict__ gws, float* __restrict__ pht) {
    int b = blockIdx.x;
    if (b < 6144) {
        int ten = b >> 11, r = b & 2047;
        const float* in = (ten == 0) ? query : (ten == 1) ? key : value;
        cvt_body(r, in, Acvt + (size_t)ten * 8192 * 512);
    } else if (b < 18432) {
        int rb = b - 6144;
        int y = rb >> 12, r = rb & 4095;
        e3_body<9>(r, (y == 0) ? Wq : (y == 1) ? Wk : Wv,
                   (y == 0) ? Eq : (y == 1) ? Ek : Ev);
    } else if (b < 67584) {
        int rb = b - 18432;
        int y = rb >> 14, r = rb & 16383;
        e3_body<11>(r, (y == 0) ? Wint : (y == 1) ? Wfin : Wout,
                    (y == 0) ? Eint : (y == 1) ? Efin : Eout);
    } else {
        tabs_body(b - 67584, gws, pht);
    }
}

// ---------------------------------------------------------------------------
// Bias matvec: out[n] = sum_k v[k]*E[n][k] + badd[n]
// ---------------------------------------------------------------------------
__global__ __launch_bounds__(256) void matvec_E(const float* __restrict__ v,
                                                const u16* __restrict__ E,
                                                const float* __restrict__ badd,
                                                float* __restrict__ out) {
    int n    = (blockIdx.x * 256 + threadIdx.x) >> 6;
    int lane = threadIdx.x & 63;
    if (n >= 2048) return;
    const u16* row = E + (size_t)n * 2048;
    float s = 0.f;
    for (int j = lane; j < 2048; j += 64) s += v[j] * bf2f(row[j]);
#pragma unroll
    for (int o = 32; o; o >>= 1) s += __shfl_down(s, o, 64);
    if (lane == 0) out[n] = s + badd[n];
}

// ---------------------------------------------------------------------------
// bf16 MFMA GEMM body (m97 structure + XCD super-tiles). NBX=16, NBY=M/128.
// OUTMODE 0: bf16 [m][n]; 1: f32 [m][n]; 2: bf16 transposed [n][m]/[b][n][s]
// ---------------------------------------------------------------------------
template<int K, int OUTMODE, int NBY>
__device__ __forceinline__ void gemm_body(int bid, u16* As, u16* Bs,
                                          const u16* __restrict__ A,
                                          const u16* __restrict__ E,
                                          const float* __restrict__ bias,
                                          void* __restrict__ outp) {
    const int t    = threadIdx.x;
    const int lane = t & 63, wave = t >> 6;
    const int wr   = wave >> 1, wc = wave & 1;
    const int lr   = lane & 15, kg = lane >> 4;
    const int l7   = lr & 7;

    constexpr int SPX = (4 * (NBY / 4)) / 8;
    const int xcd = bid & 7, p = bid >> 3;
    const int st  = xcd * SPX + (p >> 4);
    const int w   = p & 15;
    const int bx  = (st & 3) * 4 + (w & 3);
    const int by  = (st >> 2) * 4 + (w >> 2);
    const int m0  = by * 128;
    const int n0  = bx * 128;

    f32x4 acc[4][4];
#pragma unroll
    for (int i = 0; i < 4; ++i)
#pragma unroll
        for (int j = 0; j < 4; ++j) acc[i][j] = (f32x4){0.f, 0.f, 0.f, 0.f};

    const int arow = wr * 64 + lr;
    const int brow = wc * 64 + lr;

    for (int k0 = 0; k0 < K; k0 += 64) {
#pragma unroll
        for (int c = 0; c < 4; ++c) {
            int idx = t + c * 256;
            int row = idx >> 3, sl = idx & 7;
            int gsl = sl ^ (row & 7);
            gl_lds16(A + (size_t)(m0 + row) * K + k0 + gsl * 8, &As[idx * 8]);
            gl_lds16(E + (size_t)(n0 + row) * K + k0 + gsl * 8, &Bs[idx * 8]);
        }
        __syncthreads();
#pragma unroll
        for (int ks = 0; ks < 2; ++ks) {
            const int slot = (ks * 4 + kg) ^ l7;
            s16x8 av[4], bv[4];
#pragma unroll
            for (int mi = 0; mi < 4; ++mi)
                av[mi] = *(const s16x8*)&As[(arow + mi * 16) * 64 + slot * 8];
#pragma unroll
            for (int ni = 0; ni < 4; ++ni)
                bv[ni] = *(const s16x8*)&Bs[(brow + ni * 16) * 64 + slot * 8];
#pragma unroll
            for (int mi = 0; mi < 4; ++mi)
#pragma unroll
                for (int ni = 0; ni < 4; ++ni)
                    acc[mi][ni] = __builtin_amdgcn_mfma_f32_16x16x32_bf16(
                        av[mi], bv[ni], acc[mi][ni], 0, 0, 0);
        }
        __syncthreads();
    }

#pragma unroll
    for (int ni = 0; ni < 4; ++ni) {
        int n = n0 + wc * 64 + ni * 16 + lr;
        float bvl = bias ? bias[n] : 0.0f;
#pragma unroll
        for (int mi = 0; mi < 4; ++mi) {
#pragma unroll
            for (int r = 0; r < 4; ++r) {
                int m = m0 + wr * 64 + mi * 16 + kg * 4 + r;
                float val = acc[mi][ni][r] + bvl;
                if constexpr (OUTMODE == 0) {
                    ((u16*)outp)[(size_t)m * 2048 + n] = f2bf(val);
                } else if constexpr (OUTMODE == 1) {
                    ((float*)outp)[(size_t)m * 2048 + n] = val;
                } else {
                    int b = m >> 11, s = m & 2047;
                    ((u16*)outp)[((size_t)b * 2048 + n) * 2048 + s] = f2bf(val);
                }
            }
        }
    }
}

template<int K, int OUTMODE, int NBY>
__global__ __launch_bounds__(256) void gemm2(const u16* __restrict__ A,
                                             const u16* __restrict__ E,
                                             const float* __restrict__ bias,
                                             void* __restrict__ outp) {
    __shared__ u16 As[128 * 64];
    __shared__ u16 Bs[128 * 64];
    gemm_body<K, OUTMODE, NBY>(blockIdx.x, As, Bs, A, E, bias, outp);
}

// Layer-A fat kernel: combine1 (256, FIRST) + projQ (1024) + projK (1024)
__global__ __launch_bounds__(256) void gemm_fatA(const u16* __restrict__ Aq,
                                                 const u16* __restrict__ Eq,
                                                 const float* __restrict__ bq,
                                                 void* __restrict__ Qt,
                                                 const u16* __restrict__ Ak,
                                                 const u16* __restrict__ Ek,
                                                 const float* __restrict__ bk,
                                                 void* __restrict__ Kt,
                                                 const u16* __restrict__ Efin,
                                                 const u16* __restrict__ EintT,
                                                 void* __restrict__ T1T) {
    __shared__ u16 As[128 * 64];
    __shared__ u16 Bs[128 * 64];
    int bid = blockIdx.x;
    if (bid < 256) {
        gemm_body<2048, 2, 16>(bid, As, Bs, Efin, EintT, nullptr, T1T);
    } else {
        int pid = bid - 256;
        if (pid < 1024)
            gemm_body<512, 2, 64>(pid, As, Bs, Aq, Eq, bq, Qt);
        else
            gemm_body<512, 2, 64>(pid - 1024, As, Bs, Ak, Ek, bk, Kt);
    }
}

// ---------------------------------------------------------------------------
// In-place FFT, bitrev input -> natural output.
// Twiddle-free radix-4 (stages 0-1) + radix-8 passes (stages 2-4, 5-7, 8-10).
// ---------------------------------------------------------------------------
template<int LH, int OFF>
__device__ __forceinline__ void r8pass(float* re, float* im,
                                       const float2* __restrict__ wt, int t) {
    constexpr int h = 1 << LH;
    __syncthreads();
    const int j  = t & (h - 1);
    const int i0 = ((t >> LH) << (LH + 3)) | j;
    const float2 w = wt[OFF + j];               // t3 = cis(-pi*j/(4h))
    const float t2r = w.x * w.x - w.y * w.y;    // t2 = t3^2
    const float t2i = 2.f * w.x * w.y;
    const float t1r = t2r * t2r - t2i * t2i;    // t1 = t3^4
    const float t1i = 2.f * t2r * t2i;
    const float S = 0.70710678118654752f;
    const float Ac = S * (w.x + w.y);           // t3*cis(-pi/4) = (Ac, Bc)
    const float Bc = S * (w.y - w.x);           // t3*cis(-3pi/4) = (Bc, -Ac)

    float xr[8], xi[8];
    int p[8];
#pragma unroll
    for (int k = 0; k < 8; ++k) {
        p[k] = PD(i0 + k * h);
        xr[k] = re[p[k]]; xi[k] = im[p[k]];
    }
#pragma unroll
    for (int kp = 0; kp < 8; kp += 2) {
        float tr = t1r * xr[kp + 1] - t1i * xi[kp + 1];
        float ti = t1r * xi[kp + 1] + t1i * xr[kp + 1];
        float ar = xr[kp], ai = xi[kp];
        xr[kp] = ar + tr;     xi[kp] = ai + ti;
        xr[kp + 1] = ar - tr; xi[kp + 1] = ai - ti;
    }
#pragma unroll
    for (int q = 0; q < 2; ++q) {
        int b0 = q * 4;
        {
            float tr = t2r * xr[b0 + 2] - t2i * xi[b0 + 2];
            float ti = t2r * xi[b0 + 2] + t2i * xr[b0 + 2];
            float ar = xr[b0], ai = xi[b0];
            xr[b0] = ar + tr;     xi[b0] = ai + ti;
            xr[b0 + 2] = ar - tr; xi[b0 + 2] = ai - ti;
        }
        {
            float tr = t2i * xr[b0 + 3] + t2r * xi[b0 + 3];
            float ti = t2i * xi[b0 + 3] - t2r * xr[b0 + 3];
            float ar = xr[b0 + 1], ai = xi[b0 + 1];
            xr[b0 + 1] = ar + tr; xi[b0 + 1] = ai + ti;
            xr[b0 + 3] = ar - tr; xi[b0 + 3] = ai - ti;
        }
    }
    {
        float tr = w.x * xr[4] - w.y * xi[4];
        float ti = w.x * xi[4] + w.y * xr[4];
        float ar = xr[0], ai = xi[0];
        xr[0] = ar + tr; xi[0] = ai + ti;
        xr[4] = ar - tr; xi[4] = ai - ti;
    }
    {
        float tr = Ac * xr[5] - Bc * xi[5];
        float ti = Ac * xi[5] + Bc * xr[5];
        float ar = xr[1], ai = xi[1];
        xr[1] = ar + tr; xi[1] = ai + ti;
        xr[5] = ar - tr; xi[5] = ai - ti;
    }
    {
        float tr = w.y * xr[6] + w.x * xi[6];
        float ti = w.y * xi[6] - w.x * xr[6];
        float ar = xr[2], ai = xi[2];
        xr[2] = ar + tr; xi[2] = ai + ti;
        xr[6] = ar - tr; xi[6] = ai - ti;
    }
    {
        float tr = Bc * xr[7] + Ac * xi[7];
        float ti = Bc * xi[7] - Ac * xr[7];
        float ar = xr[3], ai = xi[3];
        xr[3] = ar + tr; xi[3] = ai + ti;
        xr[7] = ar - tr; xi[7] = ai - ti;
    }
#pragma unroll
    for (int k = 0; k < 8; ++k) { re[p[k]] = xr[k]; im[p[k]] = xi[k]; }
}

__device__ void fft2048(float* re, float* im, const float2* __restrict__ wt, int t) {
    __syncthreads();   // input scatter complete
#pragma unroll
    for (int u = 0; u < 2; ++u) {
        int i0 = (t + u * 256) << 2;
        int p0 = PD(i0);
        float x0r = re[p0],     x0i = im[p0];
        float x1r = re[p0 + 1], x1i = im[p0 + 1];
        float x2r = re[p0 + 2], x2i = im[p0 + 2];
        float x3r = re[p0 + 3], x3i = im[p0 + 3];
        float ar = x0r + x1r, ai = x0i + x1i;
        float br = x0r - x1r, bi = x0i - x1i;
        float cr = x2r + x3r, ci = x2i + x3i;
        float dr = x2r - x3r, di = x2i - x3i;
        re[p0]     = ar + cr; im[p0]     = ai + ci;
        re[p0 + 2] = ar - cr; im[p0 + 2] = ai - ci;
        re[p0 + 1] = br + di; im[p0 + 1] = bi - dr;
        re[p0 + 3] = br - di; im[p0 + 3] = bi + dr;
    }
    r8pass<2, 0>(re, im, wt, t);
    r8pass<5, 4>(re, im, wt, t);
    r8pass<8, 36>(re, im, wt, t);
    __syncthreads();
}

// ---------------------------------------------------------------------------
// Spectral body: 2 channels, packed FFTs; writes WEIGHTS to Wt.
// Wt may alias Qt: each block reads ONLY its own 2 channels (fully consumed
// before the final write) and writes ONLY those same 2 channels.
// ---------------------------------------------------------------------------
__device__ void spectral_body(int sbid, float* zre, float* zim, float2* wt,
                              const u16* __restrict__ Qt,
                              const u16* __restrict__ Kt,
                              u16* __restrict__ Wt,
                              const float* __restrict__ alpha,
                              const float2* __restrict__ gws,
                              const float* __restrict__ gph) {
    const int t  = threadIdx.x;
    const int b  = sbid >> 10;
    const int cp = sbid & 1023;
    const int c0 = cp * 2;
    const size_t base0 = ((size_t)b * 2048 + c0) * 2048;
    const size_t base1 = base0 + 2048;

    for (int i = t; i < 292; i += 256) wt[i] = gws[i];

    float ph[4];
    float PH1r[4], PH1i[4], PH2r[4], PH2i[4];
    float ph24 = 0.f, PH24_1 = 0.f, PH24_2 = 0.f;

#pragma unroll
    for (int ch = 0; ch < 2; ++ch) {
        const size_t base = ch ? base1 : base0;
        const u16* Qp = Qt + base;
        const u16* Kp = Kt + base;
        __syncthreads();
#pragma unroll
        for (int u = 0; u < 8; ++u) {
            int s = t + u * 256;
            int r = __brev((unsigned)s) >> 21;
            zre[PD(r)] = bf2f(Qp[s]);
            zim[PD(r)] = bf2f(Kp[s]);
        }
        fft2048(zre, zim, wt, t);
        const float ac = alpha[c0 + ch];
#pragma unroll
        for (int u = 0; u < 4; ++u) {
            int k = t + u * 256;
            int m = (2048 - k) & 2047;
            float ar = zre[PD(k)], ai = zim[PD(k)];
            float br = zre[PD(m)], bi = zim[PD(m)];
            float qr = 0.5f * (ar + br), qi = 0.5f * (ai - bi);
            float kr = 0.5f * (ai + bi), ki = 0.5f * (br - ar);
            float cr = qr * kr + qi * ki;
            float ci = qi * kr - qr * ki;
            if (ch == 0) ph[u] = gph[min(k, 2048 - k)];
            float fr, fi;
            __sincosf(ph[u] * ac, &fi, &fr);
            float Pkr = cr * fr - ci * fi, Pki = cr * fi + ci * fr;
            float qr2 = 0.5f * (br + ar), qi2 = 0.5f * (bi - ai);
            float kr2 = 0.5f * (bi + ai), ki2 = 0.5f * (ar - br);
            float cr2 = qr2 * kr2 + qi2 * ki2;
            float ci2 = qi2 * kr2 - qr2 * ki2;
            float Pmr = cr2 * fr - ci2 * fi, Pmi = cr2 * fi + ci2 * fr;
            float hr = 0.5f * (Pkr + Pmr), hi = 0.5f * (Pki - Pmi);
            if (ch == 0) { PH1r[u] = hr; PH1i[u] = hi; }
            else         { PH2r[u] = hr; PH2i[u] = hi; }
        }
        if (t == 0) {
            float ar = zre[PD(1024)], ai = zim[PD(1024)];
            float cr = ar * ai;
            if (ch == 0) ph24 = gph[1024];
            float fr, fi;
            __sincosf(ph24 * ac, &fi, &fr);
            if (ch == 0) PH24_1 = cr * fr; else PH24_2 = cr * fr;
        }
    }

    __syncthreads();
#pragma unroll
    for (int u = 0; u < 4; ++u) {
        int k = t + u * 256;
        int m = (2048 - k) & 2047;
        int rk = __brev((unsigned)k) >> 21;
        int rm = __brev((unsigned)m) >> 21;
        zre[PD(rk)] = PH1r[u] - PH2i[u];
        zim[PD(rk)] = PH1i[u] + PH2r[u];
        zre[PD(rm)] = PH1r[u] + PH2i[u];
        zim[PD(rm)] = PH2r[u] - PH1i[u];
    }
    if (t == 0) {
        zre[PD(1)] = PH24_1;
        zim[PD(1)] = PH24_2;
    }
    fft2048(zre, zim, wt, t);

#pragma unroll
    for (int u = 0; u < 8; ++u) {
        int s = t + u * 256;
        int j = (2048 - s) & 2047;
        Wt[base0 + s] = f2bf(zre[PD(j)] * (1.0f / 2048.0f));
        Wt[base1 + s] = f2bf(zim[PD(j)] * (1.0f / 2048.0f));
    }
}

// Layer-B fat kernel: combine2 (256, FIRST — full kernel window to finish) +
// spectral (4096) + projV (1024) interleaved 4:1. Wt aliases Qt (in-place),
// so Eout/T1T stay live for combine2.
__global__ __launch_bounds__(256) void fat_specv(const u16* __restrict__ Qt,
                                                 const u16* __restrict__ Kt,
                                                 u16* __restrict__ Wt,
                                                 const float* __restrict__ alpha,
                                                 const float2* __restrict__ gws,
                                                 const float* __restrict__ gph,
                                                 const u16* __restrict__ Av,
                                                 const u16* __restrict__ Ev,
                                                 const float* __restrict__ bvb,
                                                 void* __restrict__ Vt,
                                                 const u16* __restrict__ Eout,
                                                 const u16* __restrict__ T1T,
                                                 void* __restrict__ Ecomb) {
    __shared__ __align__(16) char smem[32768];
    int bid = blockIdx.x;
    if (bid < 256) {
        gemm_body<2048, 0, 16>(bid, (u16*)smem, (u16*)(smem + 16384),
                               Eout, T1T, nullptr, Ecomb);
        return;
    }
    bid -= 256;
    if (bid % 5 == 4) {
        gemm_body<512, 2, 64>(bid / 5, (u16*)smem, (u16*)(smem + 16384),
                              Av, Ev, bvb, Vt);
    } else {
        int sbid = (bid / 5) * 4 + (bid % 5);
        spectral_body(sbid, (float*)smem, (float*)(smem + 8960),
                      (float2*)(smem + 17920), Qt, Kt, Wt, alpha, gws, gph);
    }
}

// ---------------------------------------------------------------------------
// Plain transpose (EintT) and fused multiply-transpose (attn = (W .* V)^T)
// ---------------------------------------------------------------------------
__global__ __launch_bounds__(256) void transpose_k(const u16* __restrict__ in,
                                                   u16* __restrict__ out) {
    __shared__ u16 tile[32][33];
    int b = blockIdx.z;
    int c0 = blockIdx.x * 32, s0 = blockIdx.y * 32;
    int tx = threadIdx.x, ty = threadIdx.y;
#pragma unroll
    for (int dy = 0; dy < 32; dy += 8)
        tile[ty + dy][tx] = in[((size_t)b * 2048 + c0 + ty + dy) * 2048 + s0 + tx];
    __syncthreads();
#pragma unroll
    for (int dy = 0; dy < 32; dy += 8)
        out[((size_t)b * 2048 + s0 + ty + dy) * 2048 + c0 + tx] = tile[tx][ty + dy];
}

__global__ __launch_bounds__(256) void transpose_mul(const u16* __restrict__ W,
                                                     const u16* __restrict__ V,
                                                     u16* __restrict__ out) {
    __shared__ u16 tile[32][33];
    int b = blockIdx.z;
    int c0 = blockIdx.x * 32, s0 = blockIdx.y * 32;
    int tx = threadIdx.x, ty = threadIdx.y;
#pragma unroll
    for (int dy = 0; dy < 32; dy += 8) {
        size_t idx = ((size_t)b * 2048 + c0 + ty + dy) * 2048 + s0 + tx;
        tile[ty + dy][tx] = f2bf(bf2f(W[idx]) * bf2f(V[idx]));
    }
    __syncthreads();
#pragma unroll
    for (int dy = 0; dy < 32; dy += 8)
        out[((size_t)b * 2048 + s0 + ty + dy) * 2048 + c0 + tx] = tile[tx][ty + dy];
}

// ---------------------------------------------------------------------------
extern "C" void kernel_launch(void* const* d_in, const int* in_sizes, int n_in,
                              void* d_out, int out_size, void* d_ws, size_t ws_size,
                              hipStream_t stream) {
    const float* query = (const float*)d_in[0];
    const float* key   = (const float*)d_in[1];
    const float* value = (const float*)d_in[2];
    const float* Wq    = (const float*)d_in[3];
    const float* bq    = (const float*)d_in[4];
    const float* Wk    = (const float*)d_in[5];
    const float* bk    = (const float*)d_in[6];
    const float* Wv    = (const float*)d_in[7];
    const float* bv    = (const float*)d_in[8];
    const float* alpha = (const float*)d_in[9];
    const float* Wint  = (const float*)d_in[10];
    const float* bint  = (const float*)d_in[11];
    const float* Wfin  = (const float*)d_in[12];
    const float* bfin  = (const float*)d_in[13];
    const float* Wout  = (const float*)d_in[14];
    const float* bout  = (const float*)d_in[15];

    char* ws = (char*)d_ws;
    size_t off = 0;
    auto alloc = [&](size_t bytes) -> void* {
        void* p = ws + off;
        off += (bytes + 255) & ~(size_t)255;
        return p;
    };
    u16* Eq   = (u16*)alloc((size_t)2048 * 512 * 2);
    u16* Ek   = (u16*)alloc((size_t)2048 * 512 * 2);
    u16* Ev   = (u16*)alloc((size_t)2048 * 512 * 2);
    u16* Eint = (u16*)alloc((size_t)2048 * 2048 * 2);   // becomes Ecomb
    u16* Efin = (u16*)alloc((size_t)2048 * 2048 * 2);
    u16* Eout = (u16*)alloc((size_t)2048 * 2048 * 2);
    u16* EintT= (u16*)alloc((size_t)2048 * 2048 * 2);
    u16* T1T  = (u16*)alloc((size_t)2048 * 2048 * 2);
    u16* Qt   = (u16*)alloc((size_t)4 * 2048 * 2048 * 2);
    u16* Kt   = (u16*)alloc((size_t)4 * 2048 * 2048 * 2);
    u16* Vt   = (u16*)alloc((size_t)4 * 2048 * 2048 * 2);
    u16* attn = (u16*)alloc((size_t)8192 * 2048 * 2);
    float2* gws = (float2*)alloc(292 * 8);
    float*  pht = (float*)alloc(1025 * 4);
    float*  bv1 = (float*)alloc(2048 * 4);
    float*  bv2 = (float*)alloc(2048 * 4);
    u16* Ecomb = Eint;  // Eint (weights form) dead after EintT is built
    u16* Wt    = Qt;    // in-place: spectral reads its own channels fully
                        // before writing; Eout/T1T stay live for combine2
    u16* Aq = attn;
    u16* Ak = attn + (size_t)8192 * 512;
    u16* Av = attn + (size_t)8192 * 1024;

    // one fused prep dispatch: cvt x3, E<9> x3, E<11> x3, tables
    fat_prep<<<67589, 256, 0, stream>>>(query, key, value, Aq,
                                        Wq, Wk, Wv, Eq, Ek, Ev,
                                        Wint, Wfin, Wout, Eint, Efin, Eout,
                                        gws, pht);

    dim3 gt1(64, 64, 1);
    transpose_k<<<gt1, dim3(32, 8), 0, stream>>>(Eint, EintT);

    // Layer A: combine1 (first) + projQ + projK
    gemm_fatA<<<2304, 256, 0, stream>>>(Aq, Eq, bq, Qt, Ak, Ek, bk, Kt,
                                        Efin, EintT, T1T);

    // combined bias: bv2 = (bint*Efin^T + bfin)*Eout^T + bout
    matvec_E<<<512, 256, 0, stream>>>(bint, Efin, bfin, bv1);
    matvec_E<<<512, 256, 0, stream>>>(bv1,  Eout, bout, bv2);

    // Layer B: combine2 (first) + spectral (in-place over Qt) + projV
    fat_specv<<<5376, 256, 0, stream>>>(Qt, Kt, Wt, alpha, gws, pht,
                                        Av, Ev, bv, Vt, Eout, T1T, Ecomb);

    // attn[(b,s)][c] = W[b][c][s] * V[b][c][s]
    dim3 gt(64, 64, 4);
    transpose_mul<<<gt, dim3(32, 8), 0, stream>>>(Wt, Vt, attn);

    // single fused trailing linear
    gemm2<2048, 1, 64><<<1024, 256, 0, stream>>>(attn, Ecomb, bv2, (float*)d_out);
}

// Round 20
// 354.164 us; speedup vs baseline: 1.0245x; 1.0245x over previous
//
#include <hip/hip_runtime.h>
#include <hip/hip_bf16.h>
#include <cstdint>

typedef unsigned short u16;
typedef u16  u16x4 __attribute__((ext_vector_type(4)));
typedef u16  u16x8 __attribute__((ext_vector_type(8)));
typedef short s16x8 __attribute__((ext_vector_type(8)));
typedef float f32x4 __attribute__((ext_vector_type(4)));

#define PI_F 3.14159265358979323846f
#define PD(i) ((i) + 3 * ((i) >> 5))

static __device__ __forceinline__ u16 f2bf(float f) {
    union { float f; unsigned u; } v; v.f = f;
    unsigned r = v.u + 0x7fffu + ((v.u >> 16) & 1u);
    return (u16)(r >> 16);
}
static __device__ __forceinline__ float bf2f(u16 h) {
    union { unsigned u; float f; } v; v.u = ((unsigned)h) << 16;
    return v.f;
}

__device__ __forceinline__ void gl_lds16(const u16* g, u16* l) {
    __builtin_amdgcn_global_load_lds(
        (const __attribute__((address_space(1))) unsigned int*)g,
        (__attribute__((address_space(3))) unsigned int*)l, 16, 0, 0);
}

// ---------------------------------------------------------------------------
// Fused prep: cvt (f32->bf16, 3 tensors) + build_E (x6) + tables, one grid.
// ---------------------------------------------------------------------------
__device__ __forceinline__ void cvt_body(int blk, const float* __restrict__ in,
                                         u16* __restrict__ o) {
    int i = blk * 256 + threadIdx.x;
    float4 a = ((const float4*)in)[2 * i];
    float4 b = ((const float4*)in)[2 * i + 1];
    u16x8 vv;
    vv[0] = f2bf(a.x); vv[1] = f2bf(a.y); vv[2] = f2bf(a.z); vv[3] = f2bf(a.w);
    vv[4] = f2bf(b.x); vv[5] = f2bf(b.y); vv[6] = f2bf(b.z); vv[7] = f2bf(b.w);
    ((u16x8*)o)[i] = vv;
}

template<int LOGK>
__device__ __forceinline__ void e3_body(int blk, const float* __restrict__ W,
                                        u16* __restrict__ E) {
    const int K = 1 << LOGK;
    int idx = blk * 256 + threadIdx.x;
    int n = idx >> LOGK, k = idx & (K - 1);
    int o = n >> 2, c = n & 3, i = k >> 2, cp = k & 3;
    const int   qm[4][4] = {{0,1,2,3},{1,0,3,2},{2,3,0,1},{3,2,1,0}};
    const float qs[4][4] = {{1.f,-1.f,-1.f,-1.f},{1.f,1.f,1.f,-1.f},
                            {1.f,-1.f,1.f,1.f},{1.f,1.f,-1.f,1.f}};
    int in_q = K >> 2;
    float w = W[(size_t)qm[c][cp] * 512 * in_q + (size_t)o * in_q + i] * qs[c][cp];
    E[idx] = f2bf(w);
}

// r8 twiddle tables: h=4 @0 (4) | h=32 @4 (32) | h=256 @36 (256) -> 292.
__device__ __forceinline__ void tabs_body(int blk, float2* __restrict__ gws,
                                          float* __restrict__ ph) {
    int i = blk * 256 + threadIdx.x;
    if (i < 292) {
        int off, denom;
        if (i < 4)       { off = 0;  denom = 16;   }
        else if (i < 36) { off = 4;  denom = 128;  }
        else             { off = 36; denom = 1024; }
        float a = (-PI_F) * (float)(i - off) / (float)denom;
        gws[i] = make_float2(cosf(a), sinf(a));
    }
    if (i <= 1024) {
        ph[i] = atanf(logf((float)i * (1.0f / 2048.0f) + 1e-6f));
    }
}

__global__ __launch_bounds__(256) void fat_prep(
        const float* __restrict__ query, const float* __restrict__ key,
        const float* __restrict__ value, u16* __restrict__ Acvt,
        const float* __restrict__ Wq, const float* __restrict__ Wk,
        const float* __restrict__ Wv, u16* __restrict__ Eq,
        u16* __restrict__ Ek, u16* __restrict__ Ev,
        const float* __restrict__ Wint, const float* __restrict__ Wfin,
        const float* __restrict__ Wout, u16* __restrict__ Eint,
        u16* __restrict__ Efin, u16* __restrict__ Eout,
        float2* __restrict__ gws, float* __restrict__ pht) {
    int b = blockIdx.x;
    if (b < 6144) {
        int ten = b >> 11, r = b & 2047;
        const float* in = (ten == 0) ? query : (ten == 1) ? key : value;
        cvt_body(r, in, Acvt + (size_t)ten * 8192 * 512);
    } else if (b < 18432) {
        int rb = b - 6144;
        int y = rb >> 12, r = rb & 4095;
        e3_body<9>(r, (y == 0) ? Wq : (y == 1) ? Wk : Wv,
                   (y == 0) ? Eq : (y == 1) ? Ek : Ev);
    } else if (b < 67584) {
        int rb = b - 18432;
        int y = rb >> 14, r = rb & 16383;
        e3_body<11>(r, (y == 0) ? Wint : (y == 1) ? Wfin : Wout,
                    (y == 0) ? Eint : (y == 1) ? Efin : Eout);
    } else {
        tabs_body(b - 67584, gws, pht);
    }
}

// ---------------------------------------------------------------------------
// Bias matvec body: out[n] = sum_k v[k]*E[n][k] + badd[n]   (4 rows/block)
// ---------------------------------------------------------------------------
__device__ __forceinline__ void mv_body(int blk, const float* __restrict__ v,
                                        const u16* __restrict__ E,
                                        const float* __restrict__ badd,
                                        float* __restrict__ out) {
    int n    = (blk * 256 + threadIdx.x) >> 6;
    int lane = threadIdx.x & 63;
    if (n >= 2048) return;
    const u16* row = E + (size_t)n * 2048;
    float s = 0.f;
    for (int j = lane; j < 2048; j += 64) s += v[j] * bf2f(row[j]);
#pragma unroll
    for (int o = 32; o; o >>= 1) s += __shfl_down(s, o, 64);
    if (lane == 0) out[n] = s + badd[n];
}

// ---------------------------------------------------------------------------
// bf16 MFMA GEMM body (m97 structure + XCD super-tiles). NBX=16, NBY=M/128.
// OUTMODE 0: bf16 [m][n]; 1: f32 [m][n]; 2: bf16 transposed [n][m]/[b][n][s]
// ---------------------------------------------------------------------------
template<int K, int OUTMODE, int NBY>
__device__ __forceinline__ void gemm_body(int bid, u16* As, u16* Bs,
                                          const u16* __restrict__ A,
                                          const u16* __restrict__ E,
                                          const float* __restrict__ bias,
                                          void* __restrict__ outp) {
    const int t    = threadIdx.x;
    const int lane = t & 63, wave = t >> 6;
    const int wr   = wave >> 1, wc = wave & 1;
    const int lr   = lane & 15, kg = lane >> 4;
    const int l7   = lr & 7;

    constexpr int SPX = (4 * (NBY / 4)) / 8;
    const int xcd = bid & 7, p = bid >> 3;
    const int st  = xcd * SPX + (p >> 4);
    const int w   = p & 15;
    const int bx  = (st & 3) * 4 + (w & 3);
    const int by  = (st >> 2) * 4 + (w >> 2);
    const int m0  = by * 128;
    const int n0  = bx * 128;

    f32x4 acc[4][4];
#pragma unroll
    for (int i = 0; i < 4; ++i)
#pragma unroll
        for (int j = 0; j < 4; ++j) acc[i][j] = (f32x4){0.f, 0.f, 0.f, 0.f};

    const int arow = wr * 64 + lr;
    const int brow = wc * 64 + lr;

    for (int k0 = 0; k0 < K; k0 += 64) {
#pragma unroll
        for (int c = 0; c < 4; ++c) {
            int idx = t + c * 256;
            int row = idx >> 3, sl = idx & 7;
            int gsl = sl ^ (row & 7);
            gl_lds16(A + (size_t)(m0 + row) * K + k0 + gsl * 8, &As[idx * 8]);
            gl_lds16(E + (size_t)(n0 + row) * K + k0 + gsl * 8, &Bs[idx * 8]);
        }
        __syncthreads();
#pragma unroll
        for (int ks = 0; ks < 2; ++ks) {
            const int slot = (ks * 4 + kg) ^ l7;
            s16x8 av[4], bv[4];
#pragma unroll
            for (int mi = 0; mi < 4; ++mi)
                av[mi] = *(const s16x8*)&As[(arow + mi * 16) * 64 + slot * 8];
#pragma unroll
            for (int ni = 0; ni < 4; ++ni)
                bv[ni] = *(const s16x8*)&Bs[(brow + ni * 16) * 64 + slot * 8];
#pragma unroll
            for (int mi = 0; mi < 4; ++mi)
#pragma unroll
                for (int ni = 0; ni < 4; ++ni)
                    acc[mi][ni] = __builtin_amdgcn_mfma_f32_16x16x32_bf16(
                        av[mi], bv[ni], acc[mi][ni], 0, 0, 0);
        }
        __syncthreads();
    }

#pragma unroll
    for (int ni = 0; ni < 4; ++ni) {
        int n = n0 + wc * 64 + ni * 16 + lr;
        float bvl = bias ? bias[n] : 0.0f;
#pragma unroll
        for (int mi = 0; mi < 4; ++mi) {
#pragma unroll
            for (int r = 0; r < 4; ++r) {
                int m = m0 + wr * 64 + mi * 16 + kg * 4 + r;
                float val = acc[mi][ni][r] + bvl;
                if constexpr (OUTMODE == 0) {
                    ((u16*)outp)[(size_t)m * 2048 + n] = f2bf(val);
                } else if constexpr (OUTMODE == 1) {
                    ((float*)outp)[(size_t)m * 2048 + n] = val;
                } else {
                    int b = m >> 11, s = m & 2047;
                    ((u16*)outp)[((size_t)b * 2048 + n) * 2048 + s] = f2bf(val);
                }
            }
        }
    }
}

template<int K, int OUTMODE, int NBY>
__global__ __launch_bounds__(256) void gemm2(const u16* __restrict__ A,
                                             const u16* __restrict__ E,
                                             const float* __restrict__ bias,
                                             void* __restrict__ outp) {
    __shared__ u16 As[128 * 64];
    __shared__ u16 Bs[128 * 64];
    gemm_body<K, OUTMODE, NBY>(blockIdx.x, As, Bs, A, E, bias, outp);
}

// Layer-A fat kernel: combine1 (256, FIRST) + projQ (1024) + projK (1024)
// + matvec1 tail (512)
__global__ __launch_bounds__(256) void gemm_fatA(const u16* __restrict__ Aq,
                                                 const u16* __restrict__ Eq,
                                                 const float* __restrict__ bq,
                                                 void* __restrict__ Qt,
                                                 const u16* __restrict__ Ak,
                                                 const u16* __restrict__ Ek,
                                                 const float* __restrict__ bk,
                                                 void* __restrict__ Kt,
                                                 const u16* __restrict__ Efin,
                                                 const u16* __restrict__ EintT,
                                                 void* __restrict__ T1T,
                                                 const float* __restrict__ bint,
                                                 const float* __restrict__ bfin,
                                                 float* __restrict__ bv1) {
    __shared__ u16 As[128 * 64];
    __shared__ u16 Bs[128 * 64];
    int bid = blockIdx.x;
    if (bid < 256) {
        gemm_body<2048, 2, 16>(bid, As, Bs, Efin, EintT, nullptr, T1T);
    } else if (bid < 1280) {
        gemm_body<512, 2, 64>(bid - 256, As, Bs, Aq, Eq, bq, Qt);
    } else if (bid < 2304) {
        gemm_body<512, 2, 64>(bid - 1280, As, Bs, Ak, Ek, bk, Kt);
    } else {
        mv_body(bid - 2304, bint, Efin, bfin, bv1);
    }
}

// ---------------------------------------------------------------------------
// In-place FFT, bitrev input -> natural output.
// Twiddle-free radix-4 (stages 0-1) + radix-8 passes (stages 2-4, 5-7, 8-10).
// ---------------------------------------------------------------------------
template<int LH, int OFF>
__device__ __forceinline__ void r8pass(float* re, float* im,
                                       const float2* __restrict__ wt, int t) {
    constexpr int h = 1 << LH;
    __syncthreads();
    const int j  = t & (h - 1);
    const int i0 = ((t >> LH) << (LH + 3)) | j;
    const float2 w = wt[OFF + j];               // t3 = cis(-pi*j/(4h))
    const float t2r = w.x * w.x - w.y * w.y;    // t2 = t3^2
    const float t2i = 2.f * w.x * w.y;
    const float t1r = t2r * t2r - t2i * t2i;    // t1 = t3^4
    const float t1i = 2.f * t2r * t2i;
    const float S = 0.70710678118654752f;
    const float Ac = S * (w.x + w.y);           // t3*cis(-pi/4) = (Ac, Bc)
    const float Bc = S * (w.y - w.x);           // t3*cis(-3pi/4) = (Bc, -Ac)

    float xr[8], xi[8];
    int p[8];
#pragma unroll
    for (int k = 0; k < 8; ++k) {
        p[k] = PD(i0 + k * h);
        xr[k] = re[p[k]]; xi[k] = im[p[k]];
    }
#pragma unroll
    for (int kp = 0; kp < 8; kp += 2) {
        float tr = t1r * xr[kp + 1] - t1i * xi[kp + 1];
        float ti = t1r * xi[kp + 1] + t1i * xr[kp + 1];
        float ar = xr[kp], ai = xi[kp];
        xr[kp] = ar + tr;     xi[kp] = ai + ti;
        xr[kp + 1] = ar - tr; xi[kp + 1] = ai - ti;
    }
#pragma unroll
    for (int q = 0; q < 2; ++q) {
        int b0 = q * 4;
        {
            float tr = t2r * xr[b0 + 2] - t2i * xi[b0 + 2];
            float ti = t2r * xi[b0 + 2] + t2i * xr[b0 + 2];
            float ar = xr[b0], ai = xi[b0];
            xr[b0] = ar + tr;     xi[b0] = ai + ti;
            xr[b0 + 2] = ar - tr; xi[b0 + 2] = ai - ti;
        }
        {
            float tr = t2i * xr[b0 + 3] + t2r * xi[b0 + 3];
            float ti = t2i * xi[b0 + 3] - t2r * xr[b0 + 3];
            float ar = xr[b0 + 1], ai = xi[b0 + 1];
            xr[b0 + 1] = ar + tr; xi[b0 + 1] = ai + ti;
            xr[b0 + 3] = ar - tr; xi[b0 + 3] = ai - ti;
        }
    }
    {
        float tr = w.x * xr[4] - w.y * xi[4];
        float ti = w.x * xi[4] + w.y * xr[4];
        float ar = xr[0], ai = xi[0];
        xr[0] = ar + tr; xi[0] = ai + ti;
        xr[4] = ar - tr; xi[4] = ai - ti;
    }
    {
        float tr = Ac * xr[5] - Bc * xi[5];
        float ti = Ac * xi[5] + Bc * xr[5];
        float ar = xr[1], ai = xi[1];
        xr[1] = ar + tr; xi[1] = ai + ti;
        xr[5] = ar - tr; xi[5] = ai - ti;
    }
    {
        float tr = w.y * xr[6] + w.x * xi[6];
        float ti = w.y * xi[6] - w.x * xr[6];
        float ar = xr[2], ai = xi[2];
        xr[2] = ar + tr; xi[2] = ai + ti;
        xr[6] = ar - tr; xi[6] = ai - ti;
    }
    {
        float tr = Bc * xr[7] + Ac * xi[7];
        float ti = Bc * xi[7] - Ac * xr[7];
        float ar = xr[3], ai = xi[3];
        xr[3] = ar + tr; xi[3] = ai + ti;
        xr[7] = ar - tr; xi[7] = ai - ti;
    }
#pragma unroll
    for (int k = 0; k < 8; ++k) { re[p[k]] = xr[k]; im[p[k]] = xi[k]; }
}

__device__ void fft2048(float* re, float* im, const float2* __restrict__ wt, int t) {
    __syncthreads();   // input scatter complete
#pragma unroll
    for (int u = 0; u < 2; ++u) {
        int i0 = (t + u * 256) << 2;
        int p0 = PD(i0);
        float x0r = re[p0],     x0i = im[p0];
        float x1r = re[p0 + 1], x1i = im[p0 + 1];
        float x2r = re[p0 + 2], x2i = im[p0 + 2];
        float x3r = re[p0 + 3], x3i = im[p0 + 3];
        float ar = x0r + x1r, ai = x0i + x1i;
        float br = x0r - x1r, bi = x0i - x1i;
        float cr = x2r + x3r, ci = x2i + x3i;
        float dr = x2r - x3r, di = x2i - x3i;
        re[p0]     = ar + cr; im[p0]     = ai + ci;
        re[p0 + 2] = ar - cr; im[p0 + 2] = ai - ci;
        re[p0 + 1] = br + di; im[p0 + 1] = bi - dr;
        re[p0 + 3] = br - di; im[p0 + 3] = bi + dr;
    }
    r8pass<2, 0>(re, im, wt, t);
    r8pass<5, 4>(re, im, wt, t);
    r8pass<8, 36>(re, im, wt, t);
    __syncthreads();
}

// ---------------------------------------------------------------------------
// Spectral body: 2 channels, packed FFTs; writes WEIGHTS to Wt.
// Wt may alias Qt (in-place, per-block own channels only).
// ---------------------------------------------------------------------------
__device__ void spectral_body(int sbid, float* zre, float* zim, float2* wt,
                              const u16* __restrict__ Qt,
                              const u16* __restrict__ Kt,
                              u16* __restrict__ Wt,
                              const float* __restrict__ alpha,
                              const float2* __restrict__ gws,
                              const float* __restrict__ gph) {
    const int t  = threadIdx.x;
    const int b  = sbid >> 10;
    const int cp = sbid & 1023;
    const int c0 = cp * 2;
    const size_t base0 = ((size_t)b * 2048 + c0) * 2048;
    const size_t base1 = base0 + 2048;

    for (int i = t; i < 292; i += 256) wt[i] = gws[i];

    float ph[4];
    float PH1r[4], PH1i[4], PH2r[4], PH2i[4];
    float ph24 = 0.f, PH24_1 = 0.f, PH24_2 = 0.f;

#pragma unroll
    for (int ch = 0; ch < 2; ++ch) {
        const size_t base = ch ? base1 : base0;
        const u16* Qp = Qt + base;
        const u16* Kp = Kt + base;
        __syncthreads();
#pragma unroll
        for (int u = 0; u < 8; ++u) {
            int s = t + u * 256;
            int r = __brev((unsigned)s) >> 21;
            zre[PD(r)] = bf2f(Qp[s]);
            zim[PD(r)] = bf2f(Kp[s]);
        }
        fft2048(zre, zim, wt, t);
        const float ac = alpha[c0 + ch];
#pragma unroll
        for (int u = 0; u < 4; ++u) {
            int k = t + u * 256;
            int m = (2048 - k) & 2047;
            float ar = zre[PD(k)], ai = zim[PD(k)];
            float br = zre[PD(m)], bi = zim[PD(m)];
            float qr = 0.5f * (ar + br), qi = 0.5f * (ai - bi);
            float kr = 0.5f * (ai + bi), ki = 0.5f * (br - ar);
            float cr = qr * kr + qi * ki;
            float ci = qi * kr - qr * ki;
            if (ch == 0) ph[u] = gph[min(k, 2048 - k)];
            float fr, fi;
            __sincosf(ph[u] * ac, &fi, &fr);
            float Pkr = cr * fr - ci * fi, Pki = cr * fi + ci * fr;
            float qr2 = 0.5f * (br + ar), qi2 = 0.5f * (bi - ai);
            float kr2 = 0.5f * (bi + ai), ki2 = 0.5f * (ar - br);
            float cr2 = qr2 * kr2 + qi2 * ki2;
            float ci2 = qi2 * kr2 - qr2 * ki2;
            float Pmr = cr2 * fr - ci2 * fi, Pmi = cr2 * fi + ci2 * fr;
            float hr = 0.5f * (Pkr + Pmr), hi = 0.5f * (Pki - Pmi);
            if (ch == 0) { PH1r[u] = hr; PH1i[u] = hi; }
            else         { PH2r[u] = hr; PH2i[u] = hi; }
        }
        if (t == 0) {
            float ar = zre[PD(1024)], ai = zim[PD(1024)];
            float cr = ar * ai;
            if (ch == 0) ph24 = gph[1024];
            float fr, fi;
            __sincosf(ph24 * ac, &fi, &fr);
            if (ch == 0) PH24_1 = cr * fr; else PH24_2 = cr * fr;
        }
    }

    __syncthreads();
#pragma unroll
    for (int u = 0; u < 4; ++u) {
        int k = t + u * 256;
        int m = (2048 - k) & 2047;
        int rk = __brev((unsigned)k) >> 21;
        int rm = __brev((unsigned)m) >> 21;
        zre[PD(rk)] = PH1r[u] - PH2i[u];
        zim[PD(rk)] = PH1i[u] + PH2r[u];
        zre[PD(rm)] = PH1r[u] + PH2i[u];
        zim[PD(rm)] = PH2r[u] - PH1i[u];
    }
    if (t == 0) {
        zre[PD(1)] = PH24_1;
        zim[PD(1)] = PH24_2;
    }
    fft2048(zre, zim, wt, t);

#pragma unroll
    for (int u = 0; u < 8; ++u) {
        int s = t + u * 256;
        int j = (2048 - s) & 2047;
        Wt[base0 + s] = f2bf(zre[PD(j)] * (1.0f / 2048.0f));
        Wt[base1 + s] = f2bf(zim[PD(j)] * (1.0f / 2048.0f));
    }
}

// Layer-B fat kernel: combine2 (256, FIRST) + spectral (4096) + projV (1024)
// interleaved 4:1 + matvec2 tail (512). Wt aliases Qt.
__global__ __launch_bounds__(256) void fat_specv(const u16* __restrict__ Qt,
                                                 const u16* __restrict__ Kt,
                                                 u16* __restrict__ Wt,
                                                 const float* __restrict__ alpha,
                                                 const float2* __restrict__ gws,
                                                 const float* __restrict__ gph,
                                                 const u16* __restrict__ Av,
                                                 const u16* __restrict__ Ev,
                                                 const float* __restrict__ bvb,
                                                 void* __restrict__ Vt,
                                                 const u16* __restrict__ Eout,
                                                 const u16* __restrict__ T1T,
                                                 void* __restrict__ Ecomb,
                                                 const float* __restrict__ bv1,
                                                 const float* __restrict__ bout,
                                                 float* __restrict__ bv2) {
    __shared__ __align__(16) char smem[32768];
    int bid = blockIdx.x;
    if (bid < 256) {
        gemm_body<2048, 0, 16>(bid, (u16*)smem, (u16*)(smem + 16384),
                               Eout, T1T, nullptr, Ecomb);
        return;
    }
    if (bid >= 5376) {
        mv_body(bid - 5376, bv1, Eout, bout, bv2);
        return;
    }
    bid -= 256;
    if (bid % 5 == 4) {
        gemm_body<512, 2, 64>(bid / 5, (u16*)smem, (u16*)(smem + 16384),
                              Av, Ev, bvb, Vt);
    } else {
        int sbid = (bid / 5) * 4 + (bid % 5);
        spectral_body(sbid, (float*)smem, (float*)(smem + 8960),
                      (float2*)(smem + 17920), Qt, Kt, Wt, alpha, gws, gph);
    }
}

// ---------------------------------------------------------------------------
// Plain transpose (EintT) and fused multiply-transpose (attn = (W .* V)^T)
// ---------------------------------------------------------------------------
__global__ __launch_bounds__(256) void transpose_k(const u16* __restrict__ in,
                                                   u16* __restrict__ out) {
    __shared__ u16 tile[32][33];
    int b = blockIdx.z;
    int c0 = blockIdx.x * 32, s0 = blockIdx.y * 32;
    int tx = threadIdx.x, ty = threadIdx.y;
#pragma unroll
    for (int dy = 0; dy < 32; dy += 8)
        tile[ty + dy][tx] = in[((size_t)b * 2048 + c0 + ty + dy) * 2048 + s0 + tx];
    __syncthreads();
#pragma unroll
    for (int dy = 0; dy < 32; dy += 8)
        out[((size_t)b * 2048 + s0 + ty + dy) * 2048 + c0 + tx] = tile[tx][ty + dy];
}

// 64x64 tile, u16x4 vectorized: attn[(b,s)][c] = W[b][c][s]*V[b][c][s]
__global__ __launch_bounds__(256) void transpose_mul(const u16* __restrict__ W,
                                                     const u16* __restrict__ V,
                                                     u16* __restrict__ out) {
    __shared__ u16 tile[64][70];
    const int b  = blockIdx.z;
    const int c0 = blockIdx.x * 64, s0 = blockIdx.y * 64;
    const int t  = threadIdx.x;
    const int g  = (t & 15) * 4;      // 4-elem group offset
    const int rb = t >> 4;            // 0..15

#pragma unroll
    for (int r = 0; r < 4; ++r) {
        int c = rb + 16 * r;
        size_t idx = ((size_t)b * 2048 + c0 + c) * 2048 + s0 + g;
        u16x4 wv = *(const u16x4*)&W[idx];
        u16x4 vv = *(const u16x4*)&V[idx];
#pragma unroll
        for (int j = 0; j < 4; ++j)
            tile[c][g + j] = f2bf(bf2f(wv[j]) * bf2f(vv[j]));
    }
    __syncthreads();
#pragma unroll
    for (int r = 0; r < 4; ++r) {
        int s = rb + 16 * r;
        u16x4 o;
#pragma unroll
        for (int j = 0; j < 4; ++j) o[j] = tile[g + j][s];
        *(u16x4*)&out[((size_t)b * 2048 + s0 + s) * 2048 + c0 + g] = o;
    }
}

// ---------------------------------------------------------------------------
extern "C" void kernel_launch(void* const* d_in, const int* in_sizes, int n_in,
                              void* d_out, int out_size, void* d_ws, size_t ws_size,
                              hipStream_t stream) {
    const float* query = (const float*)d_in[0];
    const float* key   = (const float*)d_in[1];
    const float* value = (const float*)d_in[2];
    const float* Wq    = (const float*)d_in[3];
    const float* bq    = (const float*)d_in[4];
    const float* Wk    = (const float*)d_in[5];
    const float* bk    = (const float*)d_in[6];
    const float* Wv    = (const float*)d_in[7];
    const float* bv    = (const float*)d_in[8];
    const float* alpha = (const float*)d_in[9];
    const float* Wint  = (const float*)d_in[10];
    const float* bint  = (const float*)d_in[11];
    const float* Wfin  = (const float*)d_in[12];
    const float* bfin  = (const float*)d_in[13];
    const float* Wout  = (const float*)d_in[14];
    const float* bout  = (const float*)d_in[15];

    char* ws = (char*)d_ws;
    size_t off = 0;
    auto alloc = [&](size_t bytes) -> void* {
        void* p = ws + off;
        off += (bytes + 255) & ~(size_t)255;
        return p;
    };
    u16* Eq   = (u16*)alloc((size_t)2048 * 512 * 2);
    u16* Ek   = (u16*)alloc((size_t)2048 * 512 * 2);
    u16* Ev   = (u16*)alloc((size_t)2048 * 512 * 2);
    u16* Eint = (u16*)alloc((size_t)2048 * 2048 * 2);   // becomes Ecomb
    u16* Efin = (u16*)alloc((size_t)2048 * 2048 * 2);
    u16* Eout = (u16*)alloc((size_t)2048 * 2048 * 2);
    u16* EintT= (u16*)alloc((size_t)2048 * 2048 * 2);
    u16* T1T  = (u16*)alloc((size_t)2048 * 2048 * 2);
    u16* Qt   = (u16*)alloc((size_t)4 * 2048 * 2048 * 2);
    u16* Kt   = (u16*)alloc((size_t)4 * 2048 * 2048 * 2);
    u16* Vt   = (u16*)alloc((size_t)4 * 2048 * 2048 * 2);
    u16* attn = (u16*)alloc((size_t)8192 * 2048 * 2);
    float2* gws = (float2*)alloc(292 * 8);
    float*  pht = (float*)alloc(1025 * 4);
    float*  bv1 = (float*)alloc(2048 * 4);
    float*  bv2 = (float*)alloc(2048 * 4);
    u16* Ecomb = Eint;  // Eint (weights form) dead after EintT is built
    u16* Wt    = Qt;    // in-place; Eout/T1T stay live for combine2/matvec2
    u16* Aq = attn;
    u16* Ak = attn + (size_t)8192 * 512;
    u16* Av = attn + (size_t)8192 * 1024;

    // one fused prep dispatch: cvt x3, E<9> x3, E<11> x3, tables
    fat_prep<<<67589, 256, 0, stream>>>(query, key, value, Aq,
                                        Wq, Wk, Wv, Eq, Ek, Ev,
                                        Wint, Wfin, Wout, Eint, Efin, Eout,
                                        gws, pht);

    dim3 gt1(64, 64, 1);
    transpose_k<<<gt1, dim3(32, 8), 0, stream>>>(Eint, EintT);

    // Layer A: combine1 (first) + projQ + projK + matvec1 tail
    gemm_fatA<<<2816, 256, 0, stream>>>(Aq, Eq, bq, Qt, Ak, Ek, bk, Kt,
                                        Efin, EintT, T1T, bint, bfin, bv1);

    // Layer B: combine2 (first) + spectral (in-place over Qt) + projV
    //          + matvec2 tail
    fat_specv<<<5888, 256, 0, stream>>>(Qt, Kt, Wt, alpha, gws, pht,
                                        Av, Ev, bv, Vt, Eout, T1T, Ecomb,
                                        bv1, bout, bv2);

    // attn[(b,s)][c] = W[b][c][s] * V[b][c][s]  (64x64 vectorized)
    dim3 gt(32, 32, 4);
    transpose_mul<<<gt, 256, 0, stream>>>(Wt, Vt, attn);

    // single fused trailing linear
    gemm2<2048, 1, 64><<<1024, 256, 0, stream>>>(attn, Ecomb, bv2, (float*)d_out);
}

// Round 21
// 353.922 us; speedup vs baseline: 1.0252x; 1.0007x over previous
//
#include <hip/hip_runtime.h>
#include <hip/hip_bf16.h>
#include <cstdint>

typedef unsigned short u16;
typedef u16  u16x4 __attribute__((ext_vector_type(4)));
typedef u16  u16x8 __attribute__((ext_vector_type(8)));
typedef short s16x8 __attribute__((ext_vector_type(8)));
typedef float f32x4 __attribute__((ext_vector_type(4)));

#define PI_F 3.14159265358979323846f
#define PD(i) ((i) + 3 * ((i) >> 5))

static __device__ __forceinline__ u16 f2bf(float f) {
    union { float f; unsigned u; } v; v.f = f;
    unsigned r = v.u + 0x7fffu + ((v.u >> 16) & 1u);
    return (u16)(r >> 16);
}
static __device__ __forceinline__ float bf2f(u16 h) {
    union { unsigned u; float f; } v; v.u = ((unsigned)h) << 16;
    return v.f;
}

__device__ __forceinline__ void gl_lds16(const u16* g, u16* l) {
    __builtin_amdgcn_global_load_lds(
        (const __attribute__((address_space(1))) unsigned int*)g,
        (__attribute__((address_space(3))) unsigned int*)l, 16, 0, 0);
}

// ---------------------------------------------------------------------------
// Fused prep: cvt (f32->bf16 x3) + E<9> x3 + {EintT, Efin, Eout} + tables.
// Ranges: [0,6144) cvt | [6144,18432) E<9>x3 | [18432,34816) EintT |
// [34816,51200) Efin | [51200,67584) Eout | [67584,67589) tables.
// ---------------------------------------------------------------------------
__device__ __forceinline__ void cvt_body(int blk, const float* __restrict__ in,
                                         u16* __restrict__ o) {
    int i = blk * 256 + threadIdx.x;
    float4 a = ((const float4*)in)[2 * i];
    float4 b = ((const float4*)in)[2 * i + 1];
    u16x8 vv;
    vv[0] = f2bf(a.x); vv[1] = f2bf(a.y); vv[2] = f2bf(a.z); vv[3] = f2bf(a.w);
    vv[4] = f2bf(b.x); vv[5] = f2bf(b.y); vv[6] = f2bf(b.z); vv[7] = f2bf(b.w);
    ((u16x8*)o)[i] = vv;
}

__device__ __forceinline__ void hamilton(int c, int cp, int& qmv, float& qsv) {
    const int   qm[4][4] = {{0,1,2,3},{1,0,3,2},{2,3,0,1},{3,2,1,0}};
    const float qs[4][4] = {{1.f,-1.f,-1.f,-1.f},{1.f,1.f,1.f,-1.f},
                            {1.f,-1.f,1.f,1.f},{1.f,1.f,-1.f,1.f}};
    qmv = qm[c][cp]; qsv = qs[c][cp];
}

template<int LOGK>
__device__ __forceinline__ void e3_body(int blk, const float* __restrict__ W,
                                        u16* __restrict__ E) {
    const int K = 1 << LOGK;
    int idx = blk * 256 + threadIdx.x;
    int n = idx >> LOGK, k = idx & (K - 1);
    int o = n >> 2, c = n & 3, i = k >> 2, cp = k & 3;
    int qmv; float qsv; hamilton(c, cp, qmv, qsv);
    int in_q = K >> 2;
    float w = W[(size_t)qmv * 512 * in_q + (size_t)o * in_q + i] * qsv;
    E[idx] = f2bf(w);
}

// Transposed expand for 2048x2048: ET[k][n] = E[n][k], built directly.
__device__ __forceinline__ void e3t_body(int blk, const float* __restrict__ W,
                                         u16* __restrict__ ET) {
    int idx = blk * 256 + threadIdx.x;
    int k = idx >> 11, n = idx & 2047;
    int o = n >> 2, c = n & 3, i = k >> 2, cp = k & 3;
    int qmv; float qsv; hamilton(c, cp, qmv, qsv);
    float w = W[(size_t)qmv * 512 * 512 + (size_t)o * 512 + i] * qsv;
    ET[idx] = f2bf(w);
}

// r8 twiddle tables: h=4 @0 (4) | h=32 @4 (32) | h=256 @36 (256) -> 292.
__device__ __forceinline__ void tabs_body(int blk, float2* __restrict__ gws,
                                          float* __restrict__ ph) {
    int i = blk * 256 + threadIdx.x;
    if (i < 292) {
        int off, denom;
        if (i < 4)       { off = 0;  denom = 16;   }
        else if (i < 36) { off = 4;  denom = 128;  }
        else             { off = 36; denom = 1024; }
        float a = (-PI_F) * (float)(i - off) / (float)denom;
        gws[i] = make_float2(cosf(a), sinf(a));
    }
    if (i <= 1024) {
        ph[i] = atanf(logf((float)i * (1.0f / 2048.0f) + 1e-6f));
    }
}

__global__ __launch_bounds__(256) void fat_prep(
        const float* __restrict__ query, const float* __restrict__ key,
        const float* __restrict__ value, u16* __restrict__ Acvt,
        const float* __restrict__ Wq, const float* __restrict__ Wk,
        const float* __restrict__ Wv, u16* __restrict__ Eq,
        u16* __restrict__ Ek, u16* __restrict__ Ev,
        const float* __restrict__ Wint, const float* __restrict__ Wfin,
        const float* __restrict__ Wout, u16* __restrict__ EintT,
        u16* __restrict__ Efin, u16* __restrict__ Eout,
        float2* __restrict__ gws, float* __restrict__ pht) {
    int b = blockIdx.x;
    if (b < 6144) {
        int ten = b >> 11, r = b & 2047;
        const float* in = (ten == 0) ? query : (ten == 1) ? key : value;
        cvt_body(r, in, Acvt + (size_t)ten * 8192 * 512);
    } else if (b < 18432) {
        int rb = b - 6144;
        int y = rb >> 12, r = rb & 4095;
        e3_body<9>(r, (y == 0) ? Wq : (y == 1) ? Wk : Wv,
                   (y == 0) ? Eq : (y == 1) ? Ek : Ev);
    } else if (b < 34816) {
        e3t_body(b - 18432, Wint, EintT);
    } else if (b < 51200) {
        e3_body<11>(b - 34816, Wfin, Efin);
    } else if (b < 67584) {
        e3_body<11>(b - 51200, Wout, Eout);
    } else {
        tabs_body(b - 67584, gws, pht);
    }
}

// ---------------------------------------------------------------------------
// Bias matvec body: out[n] = sum_k v[k]*E[n][k] + badd[n]   (4 rows/block)
// ---------------------------------------------------------------------------
__device__ __forceinline__ void mv_body(int blk, const float* __restrict__ v,
                                        const u16* __restrict__ E,
                                        const float* __restrict__ badd,
                                        float* __restrict__ out) {
    int n    = (blk * 256 + threadIdx.x) >> 6;
    int lane = threadIdx.x & 63;
    if (n >= 2048) return;
    const u16* row = E + (size_t)n * 2048;
    float s = 0.f;
    for (int j = lane; j < 2048; j += 64) s += v[j] * bf2f(row[j]);
#pragma unroll
    for (int o = 32; o; o >>= 1) s += __shfl_down(s, o, 64);
    if (lane == 0) out[n] = s + badd[n];
}

// ---------------------------------------------------------------------------
// bf16 MFMA GEMM body (m97 structure + XCD super-tiles). NBX=16, NBY=M/128.
// OUTMODE 0: bf16 [m][n]; 1: f32 [m][n]; 2: bf16 transposed [n][m]/[b][n][s]
// ---------------------------------------------------------------------------
template<int K, int OUTMODE, int NBY>
__device__ __forceinline__ void gemm_body(int bid, u16* As, u16* Bs,
                                          const u16* __restrict__ A,
                                          const u16* __restrict__ E,
                                          const float* __restrict__ bias,
                                          void* __restrict__ outp) {
    const int t    = threadIdx.x;
    const int lane = t & 63, wave = t >> 6;
    const int wr   = wave >> 1, wc = wave & 1;
    const int lr   = lane & 15, kg = lane >> 4;
    const int l7   = lr & 7;

    constexpr int SPX = (4 * (NBY / 4)) / 8;
    const int xcd = bid & 7, p = bid >> 3;
    const int st  = xcd * SPX + (p >> 4);
    const int w   = p & 15;
    const int bx  = (st & 3) * 4 + (w & 3);
    const int by  = (st >> 2) * 4 + (w >> 2);
    const int m0  = by * 128;
    const int n0  = bx * 128;

    f32x4 acc[4][4];
#pragma unroll
    for (int i = 0; i < 4; ++i)
#pragma unroll
        for (int j = 0; j < 4; ++j) acc[i][j] = (f32x4){0.f, 0.f, 0.f, 0.f};

    const int arow = wr * 64 + lr;
    const int brow = wc * 64 + lr;

    for (int k0 = 0; k0 < K; k0 += 64) {
#pragma unroll
        for (int c = 0; c < 4; ++c) {
            int idx = t + c * 256;
            int row = idx >> 3, sl = idx & 7;
            int gsl = sl ^ (row & 7);
            gl_lds16(A + (size_t)(m0 + row) * K + k0 + gsl * 8, &As[idx * 8]);
            gl_lds16(E + (size_t)(n0 + row) * K + k0 + gsl * 8, &Bs[idx * 8]);
        }
        __syncthreads();
#pragma unroll
        for (int ks = 0; ks < 2; ++ks) {
            const int slot = (ks * 4 + kg) ^ l7;
            s16x8 av[4], bv[4];
#pragma unroll
            for (int mi = 0; mi < 4; ++mi)
                av[mi] = *(const s16x8*)&As[(arow + mi * 16) * 64 + slot * 8];
#pragma unroll
            for (int ni = 0; ni < 4; ++ni)
                bv[ni] = *(const s16x8*)&Bs[(brow + ni * 16) * 64 + slot * 8];
#pragma unroll
            for (int mi = 0; mi < 4; ++mi)
#pragma unroll
                for (int ni = 0; ni < 4; ++ni)
                    acc[mi][ni] = __builtin_amdgcn_mfma_f32_16x16x32_bf16(
                        av[mi], bv[ni], acc[mi][ni], 0, 0, 0);
        }
        __syncthreads();
    }

#pragma unroll
    for (int ni = 0; ni < 4; ++ni) {
        int n = n0 + wc * 64 + ni * 16 + lr;
        float bvl = bias ? bias[n] : 0.0f;
#pragma unroll
        for (int mi = 0; mi < 4; ++mi) {
#pragma unroll
            for (int r = 0; r < 4; ++r) {
                int m = m0 + wr * 64 + mi * 16 + kg * 4 + r;
                float val = acc[mi][ni][r] + bvl;
                if constexpr (OUTMODE == 0) {
                    ((u16*)outp)[(size_t)m * 2048 + n] = f2bf(val);
                } else if constexpr (OUTMODE == 1) {
                    ((float*)outp)[(size_t)m * 2048 + n] = val;
                } else {
                    int b = m >> 11, s = m & 2047;
                    ((u16*)outp)[((size_t)b * 2048 + n) * 2048 + s] = f2bf(val);
                }
            }
        }
    }
}

template<int K, int OUTMODE, int NBY>
__global__ __launch_bounds__(256) void gemm2(const u16* __restrict__ A,
                                             const u16* __restrict__ E,
                                             const float* __restrict__ bias,
                                             void* __restrict__ outp) {
    __shared__ u16 As[128 * 64];
    __shared__ u16 Bs[128 * 64];
    gemm_body<K, OUTMODE, NBY>(blockIdx.x, As, Bs, A, E, bias, outp);
}

// Layer-A fat kernel: combine1 (256, FIRST) + projQ (1024) + projK (1024)
// + matvec1 tail (512)
__global__ __launch_bounds__(256) void gemm_fatA(const u16* __restrict__ Aq,
                                                 const u16* __restrict__ Eq,
                                                 const float* __restrict__ bq,
                                                 void* __restrict__ Qt,
                                                 const u16* __restrict__ Ak,
                                                 const u16* __restrict__ Ek,
                                                 const float* __restrict__ bk,
                                                 void* __restrict__ Kt,
                                                 const u16* __restrict__ Efin,
                                                 const u16* __restrict__ EintT,
                                                 void* __restrict__ T1T,
                                                 const float* __restrict__ bint,
                                                 const float* __restrict__ bfin,
                                                 float* __restrict__ bv1) {
    __shared__ u16 As[128 * 64];
    __shared__ u16 Bs[128 * 64];
    int bid = blockIdx.x;
    if (bid < 256) {
        gemm_body<2048, 2, 16>(bid, As, Bs, Efin, EintT, nullptr, T1T);
    } else if (bid < 1280) {
        gemm_body<512, 2, 64>(bid - 256, As, Bs, Aq, Eq, bq, Qt);
    } else if (bid < 2304) {
        gemm_body<512, 2, 64>(bid - 1280, As, Bs, Ak, Ek, bk, Kt);
    } else {
        mv_body(bid - 2304, bint, Efin, bfin, bv1);
    }
}

// ---------------------------------------------------------------------------
// In-place FFT, bitrev input -> natural output.
// Twiddle-free radix-4 (stages 0-1) + radix-8 passes (stages 2-4, 5-7, 8-10).
// ---------------------------------------------------------------------------
template<int LH, int OFF>
__device__ __forceinline__ void r8pass(float* re, float* im,
                                       const float2* __restrict__ wt, int t) {
    constexpr int h = 1 << LH;
    __syncthreads();
    const int j  = t & (h - 1);
    const int i0 = ((t >> LH) << (LH + 3)) | j;
    const float2 w = wt[OFF + j];               // t3 = cis(-pi*j/(4h))
    const float t2r = w.x * w.x - w.y * w.y;    // t2 = t3^2
    const float t2i = 2.f * w.x * w.y;
    const float t1r = t2r * t2r - t2i * t2i;    // t1 = t3^4
    const float t1i = 2.f * t2r * t2i;
    const float S = 0.70710678118654752f;
    const float Ac = S * (w.x + w.y);           // t3*cis(-pi/4) = (Ac, Bc)
    const float Bc = S * (w.y - w.x);           // t3*cis(-3pi/4) = (Bc, -Ac)

    float xr[8], xi[8];
    int p[8];
#pragma unroll
    for (int k = 0; k < 8; ++k) {
        p[k] = PD(i0 + k * h);
        xr[k] = re[p[k]]; xi[k] = im[p[k]];
    }
#pragma unroll
    for (int kp = 0; kp < 8; kp += 2) {
        float tr = t1r * xr[kp + 1] - t1i * xi[kp + 1];
        float ti = t1r * xi[kp + 1] + t1i * xr[kp + 1];
        float ar = xr[kp], ai = xi[kp];
        xr[kp] = ar + tr;     xi[kp] = ai + ti;
        xr[kp + 1] = ar - tr; xi[kp + 1] = ai - ti;
    }
#pragma unroll
    for (int q = 0; q < 2; ++q) {
        int b0 = q * 4;
        {
            float tr = t2r * xr[b0 + 2] - t2i * xi[b0 + 2];
            float ti = t2r * xi[b0 + 2] + t2i * xr[b0 + 2];
            float ar = xr[b0], ai = xi[b0];
            xr[b0] = ar + tr;     xi[b0] = ai + ti;
            xr[b0 + 2] = ar - tr; xi[b0 + 2] = ai - ti;
        }
        {
            float tr = t2i * xr[b0 + 3] + t2r * xi[b0 + 3];
            float ti = t2i * xi[b0 + 3] - t2r * xr[b0 + 3];
            float ar = xr[b0 + 1], ai = xi[b0 + 1];
            xr[b0 + 1] = ar + tr; xi[b0 + 1] = ai + ti;
            xr[b0 + 3] = ar - tr; xi[b0 + 3] = ai - ti;
        }
    }
    {
        float tr = w.x * xr[4] - w.y * xi[4];
        float ti = w.x * xi[4] + w.y * xr[4];
        float ar = xr[0], ai = xi[0];
        xr[0] = ar + tr; xi[0] = ai + ti;
        xr[4] = ar - tr; xi[4] = ai - ti;
    }
    {
        float tr = Ac * xr[5] - Bc * xi[5];
        float ti = Ac * xi[5] + Bc * xr[5];
        float ar = xr[1], ai = xi[1];
        xr[1] = ar + tr; xi[1] = ai + ti;
        xr[5] = ar - tr; xi[5] = ai - ti;
    }
    {
        float tr = w.y * xr[6] + w.x * xi[6];
        float ti = w.y * xi[6] - w.x * xr[6];
        float ar = xr[2], ai = xi[2];
        xr[2] = ar + tr; xi[2] = ai + ti;
        xr[6] = ar - tr; xi[6] = ai - ti;
    }
    {
        float tr = Bc * xr[7] + Ac * xi[7];
        float ti = Bc * xi[7] - Ac * xr[7];
        float ar = xr[3], ai = xi[3];
        xr[3] = ar + tr; xi[3] = ai + ti;
        xr[7] = ar - tr; xi[7] = ai - ti;
    }
#pragma unroll
    for (int k = 0; k < 8; ++k) { re[p[k]] = xr[k]; im[p[k]] = xi[k]; }
}

__device__ void fft2048(float* re, float* im, const float2* __restrict__ wt, int t) {
    __syncthreads();   // input scatter complete
#pragma unroll
    for (int u = 0; u < 2; ++u) {
        int i0 = (t + u * 256) << 2;
        int p0 = PD(i0);
        float x0r = re[p0],     x0i = im[p0];
        float x1r = re[p0 + 1], x1i = im[p0 + 1];
        float x2r = re[p0 + 2], x2i = im[p0 + 2];
        float x3r = re[p0 + 3], x3i = im[p0 + 3];
        float ar = x0r + x1r, ai = x0i + x1i;
        float br = x0r - x1r, bi = x0i - x1i;
        float cr = x2r + x3r, ci = x2i + x3i;
        float dr = x2r - x3r, di = x2i - x3i;
        re[p0]     = ar + cr; im[p0]     = ai + ci;
        re[p0 + 2] = ar - cr; im[p0 + 2] = ai - ci;
        re[p0 + 1] = br + di; im[p0 + 1] = bi - dr;
        re[p0 + 3] = br - di; im[p0 + 3] = bi + dr;
    }
    r8pass<2, 0>(re, im, wt, t);
    r8pass<5, 4>(re, im, wt, t);
    r8pass<8, 36>(re, im, wt, t);
    __syncthreads();
}

// ---------------------------------------------------------------------------
// Spectral body: 2 channels, packed FFTs; writes WEIGHTS to Wt.
// Wt may alias Qt (in-place, per-block own channels only).
// ---------------------------------------------------------------------------
__device__ void spectral_body(int sbid, float* zre, float* zim, float2* wt,
                              const u16* __restrict__ Qt,
                              const u16* __restrict__ Kt,
                              u16* __restrict__ Wt,
                              const float* __restrict__ alpha,
                              const float2* __restrict__ gws,
                              const float* __restrict__ gph) {
    const int t  = threadIdx.x;
    const int b  = sbid >> 10;
    const int cp = sbid & 1023;
    const int c0 = cp * 2;
    const size_t base0 = ((size_t)b * 2048 + c0) * 2048;
    const size_t base1 = base0 + 2048;

    for (int i = t; i < 292; i += 256) wt[i] = gws[i];

    float ph[4];
    float PH1r[4], PH1i[4], PH2r[4], PH2i[4];
    float ph24 = 0.f, PH24_1 = 0.f, PH24_2 = 0.f;

#pragma unroll
    for (int ch = 0; ch < 2; ++ch) {
        const size_t base = ch ? base1 : base0;
        const u16* Qp = Qt + base;
        const u16* Kp = Kt + base;
        __syncthreads();
#pragma unroll
        for (int u = 0; u < 8; ++u) {
            int s = t + u * 256;
            int r = __brev((unsigned)s) >> 21;
            zre[PD(r)] = bf2f(Qp[s]);
            zim[PD(r)] = bf2f(Kp[s]);
        }
        fft2048(zre, zim, wt, t);
        const float ac = alpha[c0 + ch];
#pragma unroll
        for (int u = 0; u < 4; ++u) {
            int k = t + u * 256;
            int m = (2048 - k) & 2047;
            float ar = zre[PD(k)], ai = zim[PD(k)];
            float br = zre[PD(m)], bi = zim[PD(m)];
            float qr = 0.5f * (ar + br), qi = 0.5f * (ai - bi);
            float kr = 0.5f * (ai + bi), ki = 0.5f * (br - ar);
            float cr = qr * kr + qi * ki;
            float ci = qi * kr - qr * ki;
            if (ch == 0) ph[u] = gph[min(k, 2048 - k)];
            float fr, fi;
            __sincosf(ph[u] * ac, &fi, &fr);
            float Pkr = cr * fr - ci * fi, Pki = cr * fi + ci * fr;
            float qr2 = 0.5f * (br + ar), qi2 = 0.5f * (bi - ai);
            float kr2 = 0.5f * (bi + ai), ki2 = 0.5f * (ar - br);
            float cr2 = qr2 * kr2 + qi2 * ki2;
            float ci2 = qi2 * kr2 - qr2 * ki2;
            float Pmr = cr2 * fr - ci2 * fi, Pmi = cr2 * fi + ci2 * fr;
            float hr = 0.5f * (Pkr + Pmr), hi = 0.5f * (Pki - Pmi);
            if (ch == 0) { PH1r[u] = hr; PH1i[u] = hi; }
            else         { PH2r[u] = hr; PH2i[u] = hi; }
        }
        if (t == 0) {
            float ar = zre[PD(1024)], ai = zim[PD(1024)];
            float cr = ar * ai;
            if (ch == 0) ph24 = gph[1024];
            float fr, fi;
            __sincosf(ph24 * ac, &fi, &fr);
            if (ch == 0) PH24_1 = cr * fr; else PH24_2 = cr * fr;
        }
    }

    __syncthreads();
#pragma unroll
    for (int u = 0; u < 4; ++u) {
        int k = t + u * 256;
        int m = (2048 - k) & 2047;
        int rk = __brev((unsigned)k) >> 21;
        int rm = __brev((unsigned)m) >> 21;
        zre[PD(rk)] = PH1r[u] - PH2i[u];
        zim[PD(rk)] = PH1i[u] + PH2r[u];
        zre[PD(rm)] = PH1r[u] + PH2i[u];
        zim[PD(rm)] = PH2r[u] - PH1i[u];
    }
    if (t == 0) {
        zre[PD(1)] = PH24_1;
        zim[PD(1)] = PH24_2;
    }
    fft2048(zre, zim, wt, t);

#pragma unroll
    for (int u = 0; u < 8; ++u) {
        int s = t + u * 256;
        int j = (2048 - s) & 2047;
        Wt[base0 + s] = f2bf(zre[PD(j)] * (1.0f / 2048.0f));
        Wt[base1 + s] = f2bf(zim[PD(j)] * (1.0f / 2048.0f));
    }
}

// Layer-B fat kernel: combine2 (256, FIRST) + spectral (4096) + projV (1024)
// interleaved 4:1 + matvec2 tail (512). Wt aliases Qt.
__global__ __launch_bounds__(256) void fat_specv(const u16* __restrict__ Qt,
                                                 const u16* __restrict__ Kt,
                                                 u16* __restrict__ Wt,
                                                 const float* __restrict__ alpha,
                                                 const float2* __restrict__ gws,
                                                 const float* __restrict__ gph,
                                                 const u16* __restrict__ Av,
                                                 const u16* __restrict__ Ev,
                                                 const float* __restrict__ bvb,
                                                 void* __restrict__ Vt,
                                                 const u16* __restrict__ Eout,
                                                 const u16* __restrict__ T1T,
                                                 void* __restrict__ Ecomb,
                                                 const float* __restrict__ bv1,
                                                 const float* __restrict__ bout,
                                                 float* __restrict__ bv2) {
    __shared__ __align__(16) char smem[32768];
    int bid = blockIdx.x;
    if (bid < 256) {
        gemm_body<2048, 0, 16>(bid, (u16*)smem, (u16*)(smem + 16384),
                               Eout, T1T, nullptr, Ecomb);
        return;
    }
    if (bid >= 5376) {
        mv_body(bid - 5376, bv1, Eout, bout, bv2);
        return;
    }
    bid -= 256;
    if (bid % 5 == 4) {
        gemm_body<512, 2, 64>(bid / 5, (u16*)smem, (u16*)(smem + 16384),
                              Av, Ev, bvb, Vt);
    } else {
        int sbid = (bid / 5) * 4 + (bid % 5);
        spectral_body(sbid, (float*)smem, (float*)(smem + 8960),
                      (float2*)(smem + 17920), Qt, Kt, Wt, alpha, gws, gph);
    }
}

// 64x64 tile, u16x4 vectorized: attn[(b,s)][c] = W[b][c][s]*V[b][c][s]
__global__ __launch_bounds__(256) void transpose_mul(const u16* __restrict__ W,
                                                     const u16* __restrict__ V,
                                                     u16* __restrict__ out) {
    __shared__ u16 tile[64][70];
    const int b  = blockIdx.z;
    const int c0 = blockIdx.x * 64, s0 = blockIdx.y * 64;
    const int t  = threadIdx.x;
    const int g  = (t & 15) * 4;      // 4-elem group offset
    const int rb = t >> 4;            // 0..15

#pragma unroll
    for (int r = 0; r < 4; ++r) {
        int c = rb + 16 * r;
        size_t idx = ((size_t)b * 2048 + c0 + c) * 2048 + s0 + g;
        u16x4 wv = *(const u16x4*)&W[idx];
        u16x4 vv = *(const u16x4*)&V[idx];
#pragma unroll
        for (int j = 0; j < 4; ++j)
            tile[c][g + j] = f2bf(bf2f(wv[j]) * bf2f(vv[j]));
    }
    __syncthreads();
#pragma unroll
    for (int r = 0; r < 4; ++r) {
        int s = rb + 16 * r;
        u16x4 o;
#pragma unroll
        for (int j = 0; j < 4; ++j) o[j] = tile[g + j][s];
        *(u16x4*)&out[((size_t)b * 2048 + s0 + s) * 2048 + c0 + g] = o;
    }
}

// ---------------------------------------------------------------------------
extern "C" void kernel_launch(void* const* d_in, const int* in_sizes, int n_in,
                              void* d_out, int out_size, void* d_ws, size_t ws_size,
                              hipStream_t stream) {
    const float* query = (const float*)d_in[0];
    const float* key   = (const float*)d_in[1];
    const float* value = (const float*)d_in[2];
    const float* Wq    = (const float*)d_in[3];
    const float* bq    = (const float*)d_in[4];
    const float* Wk    = (const float*)d_in[5];
    const float* bk    = (const float*)d_in[6];
    const float* Wv    = (const float*)d_in[7];
    const float* bv    = (const float*)d_in[8];
    const float* alpha = (const float*)d_in[9];
    const float* Wint  = (const float*)d_in[10];
    const float* bint  = (const float*)d_in[11];
    const float* Wfin  = (const float*)d_in[12];
    const float* bfin  = (const float*)d_in[13];
    const float* Wout  = (const float*)d_in[14];
    const float* bout  = (const float*)d_in[15];

    char* ws = (char*)d_ws;
    size_t off = 0;
    auto alloc = [&](size_t bytes) -> void* {
        void* p = ws + off;
        off += (bytes + 255) & ~(size_t)255;
        return p;
    };
    u16* Eq   = (u16*)alloc((size_t)2048 * 512 * 2);
    u16* Ek   = (u16*)alloc((size_t)2048 * 512 * 2);
    u16* Ev   = (u16*)alloc((size_t)2048 * 512 * 2);
    u16* Ecomb= (u16*)alloc((size_t)2048 * 2048 * 2);   // combine2 output
    u16* Efin = (u16*)alloc((size_t)2048 * 2048 * 2);
    u16* Eout = (u16*)alloc((size_t)2048 * 2048 * 2);
    u16* EintT= (u16*)alloc((size_t)2048 * 2048 * 2);   // built directly in prep
    u16* T1T  = (u16*)alloc((size_t)2048 * 2048 * 2);
    u16* Qt   = (u16*)alloc((size_t)4 * 2048 * 2048 * 2);
    u16* Kt   = (u16*)alloc((size_t)4 * 2048 * 2048 * 2);
    u16* Vt   = (u16*)alloc((size_t)4 * 2048 * 2048 * 2);
    u16* attn = (u16*)alloc((size_t)8192 * 2048 * 2);
    float2* gws = (float2*)alloc(292 * 8);
    float*  pht = (float*)alloc(1025 * 4);
    float*  bv1 = (float*)alloc(2048 * 4);
    float*  bv2 = (float*)alloc(2048 * 4);
    u16* Wt    = Qt;    // in-place; Eout/T1T stay live for combine2/matvec2
    u16* Aq = attn;
    u16* Ak = attn + (size_t)8192 * 512;
    u16* Av = attn + (size_t)8192 * 1024;

    // fused prep: cvt x3, E<9> x3, EintT (direct transposed), Efin, Eout, tabs
    fat_prep<<<67589, 256, 0, stream>>>(query, key, value, Aq,
                                        Wq, Wk, Wv, Eq, Ek, Ev,
                                        Wint, Wfin, Wout, EintT, Efin, Eout,
                                        gws, pht);

    // Layer A: combine1 (first) + projQ + projK + matvec1 tail
    gemm_fatA<<<2816, 256, 0, stream>>>(Aq, Eq, bq, Qt, Ak, Ek, bk, Kt,
                                        Efin, EintT, T1T, bint, bfin, bv1);

    // Layer B: combine2 (first) + spectral (in-place over Qt) + projV
    //          + matvec2 tail
    fat_specv<<<5888, 256, 0, stream>>>(Qt, Kt, Wt, alpha, gws, pht,
                                        Av, Ev, bv, Vt, Eout, T1T, Ecomb,
                                        bv1, bout, bv2);

    // attn[(b,s)][c] = W[b][c][s] * V[b][c][s]  (64x64 vectorized)
    dim3 gt(32, 32, 4);
    transpose_mul<<<gt, 256, 0, stream>>>(Wt, Vt, attn);

    // single fused trailing linear
    gemm2<2048, 1, 64><<<1024, 256, 0, stream>>>(attn, Ecomb, bv2, (float*)d_out);
}

// Round 22
// 307.023 us; speedup vs baseline: 1.1818x; 1.1528x over previous
//
#include <hip/hip_runtime.h>
#include <hip/hip_bf16.h>
#include <cstdint>

typedef unsigned short u16;
typedef u16  u16x4 __attribute__((ext_vector_type(4)));
typedef u16  u16x8 __attribute__((ext_vector_type(8)));
typedef short s16x8 __attribute__((ext_vector_type(8)));
typedef float f32x4 __attribute__((ext_vector_type(4)));

#define PI_F 3.14159265358979323846f
#define PD(i) ((i) + 3 * ((i) >> 5))

static __device__ __forceinline__ u16 f2bf(float f) {
    union { float f; unsigned u; } v; v.f = f;
    unsigned r = v.u + 0x7fffu + ((v.u >> 16) & 1u);
    return (u16)(r >> 16);
}
static __device__ __forceinline__ float bf2f(u16 h) {
    union { unsigned u; float f; } v; v.u = ((unsigned)h) << 16;
    return v.f;
}

__device__ __forceinline__ void gl_lds16(const u16* g, u16* l) {
    __builtin_amdgcn_global_load_lds(
        (const __attribute__((address_space(1))) unsigned int*)g,
        (__attribute__((address_space(3))) unsigned int*)l, 16, 0, 0);
}

// ---------------------------------------------------------------------------
// Fused prep: cvt x3 + E<9> x3 + Xfin/Xout (plain cvt of W) + YtInt + tables.
// Ranges: [0,6144) cvt | [6144,18432) E<9> | [18432,18944) Xfin |
// [18944,19456) Xout | [19456,23552) YtInt | [23552,23557) tabs.
// ---------------------------------------------------------------------------
__device__ __forceinline__ void cvt_body(int blk, const float* __restrict__ in,
                                         u16* __restrict__ o) {
    int i = blk * 256 + threadIdx.x;
    float4 a = ((const float4*)in)[2 * i];
    float4 b = ((const float4*)in)[2 * i + 1];
    u16x8 vv;
    vv[0] = f2bf(a.x); vv[1] = f2bf(a.y); vv[2] = f2bf(a.z); vv[3] = f2bf(a.w);
    vv[4] = f2bf(b.x); vv[5] = f2bf(b.y); vv[6] = f2bf(b.z); vv[7] = f2bf(b.w);
    ((u16x8*)o)[i] = vv;
}

__device__ __forceinline__ void hamilton(int c, int cp, int& qmv, float& qsv) {
    const int   qm[4][4] = {{0,1,2,3},{1,0,3,2},{2,3,0,1},{3,2,1,0}};
    const float qs[4][4] = {{1.f,-1.f,-1.f,-1.f},{1.f,1.f,1.f,-1.f},
                            {1.f,-1.f,1.f,1.f},{1.f,1.f,-1.f,1.f}};
    qmv = qm[c][cp]; qsv = qs[c][cp];
}

template<int LOGK>
__device__ __forceinline__ void e3_body(int blk, const float* __restrict__ W,
                                        u16* __restrict__ E) {
    const int K = 1 << LOGK;
    int idx = blk * 256 + threadIdx.x;
    int n = idx >> LOGK, k = idx & (K - 1);
    int o = n >> 2, c = n & 3, i = k >> 2, cp = k & 3;
    int qmv; float qsv; hamilton(c, cp, qmv, qsv);
    int in_q = K >> 2;
    float w = W[(size_t)qmv * 512 * in_q + (size_t)o * in_q + i] * qsv;
    E[idx] = f2bf(w);
}

// YtInt[cb*512+i][o] = Wint[cb][o][i]  (per-comp transpose)
__device__ __forceinline__ void ytr_body(int blk, const float* __restrict__ W,
                                         u16* __restrict__ YT) {
    int b = blk * 256 + threadIdx.x;          // < 1048576
    int row = b >> 9, o = b & 511;
    int cb = row >> 9, i = row & 511;
    YT[b] = f2bf(W[((size_t)cb * 512 + o) * 512 + i]);
}

// r8 twiddle tables + phases
__device__ __forceinline__ void tabs_body(int blk, float2* __restrict__ gws,
                                          float* __restrict__ ph) {
    int i = blk * 256 + threadIdx.x;
    if (i < 292) {
        int off, denom;
        if (i < 4)       { off = 0;  denom = 16;   }
        else if (i < 36) { off = 4;  denom = 128;  }
        else             { off = 36; denom = 1024; }
        float a = (-PI_F) * (float)(i - off) / (float)denom;
        gws[i] = make_float2(cosf(a), sinf(a));
    }
    if (i <= 1024) {
        ph[i] = atanf(logf((float)i * (1.0f / 2048.0f) + 1e-6f));
    }
}

__global__ __launch_bounds__(256) void fat_prep(
        const float* __restrict__ query, const float* __restrict__ key,
        const float* __restrict__ value, u16* __restrict__ Acvt,
        const float* __restrict__ Wq, const float* __restrict__ Wk,
        const float* __restrict__ Wv, u16* __restrict__ Eq,
        u16* __restrict__ Ek, u16* __restrict__ Ev,
        const float* __restrict__ Wint, const float* __restrict__ Wfin,
        const float* __restrict__ Wout, u16* __restrict__ Xfin,
        u16* __restrict__ Xout, u16* __restrict__ YtInt,
        float2* __restrict__ gws, float* __restrict__ pht) {
    int b = blockIdx.x;
    if (b < 6144) {
        int ten = b >> 11, r = b & 2047;
        const float* in = (ten == 0) ? query : (ten == 1) ? key : value;
        cvt_body(r, in, Acvt + (size_t)ten * 8192 * 512);
    } else if (b < 18432) {
        int rb = b - 6144;
        int y = rb >> 12, r = rb & 4095;
        e3_body<9>(r, (y == 0) ? Wq : (y == 1) ? Wk : Wv,
                   (y == 0) ? Eq : (y == 1) ? Ek : Ev);
    } else if (b < 18944) {
        cvt_body(b - 18432, Wfin, Xfin);      // Xfin[ca*512+p][o] = Wfin flat
    } else if (b < 19456) {
        cvt_body(b - 18944, Wout, Xout);
    } else if (b < 23552) {
        ytr_body(b - 19456, Wint, YtInt);
    } else {
        tabs_body(b - 23552, gws, pht);
    }
}

// ---------------------------------------------------------------------------
// Bias matvec on raw quaternion weights: out[n] = sum_k v[k]*E(W)[n][k]+badd
// E(W)[4o+c][4i+cp] = qs[c][cp]*W[qm[c][cp]][o][i]; cp = lane&3 is constant.
// ---------------------------------------------------------------------------
__device__ __forceinline__ void mvW_body(int blk, const float* __restrict__ v,
                                         const float* __restrict__ W,
                                         const float* __restrict__ badd,
                                         float* __restrict__ out) {
    int n    = (blk * 256 + threadIdx.x) >> 6;
    int lane = threadIdx.x & 63;
    if (n >= 2048) return;
    int o = n >> 2, c = n & 3;
    int cp = lane & 3;
    int qmv; float qsv; hamilton(c, cp, qmv, qsv);
    const float* Wrow = W + ((size_t)qmv * 512 + o) * 512;
    float s = 0.f;
    for (int k = lane; k < 2048; k += 64) s += v[k] * Wrow[k >> 2];
    s *= qsv;
#pragma unroll
    for (int off = 32; off; off >>= 1) s += __shfl_down(s, off, 64);
    if (lane == 0) out[n] = s + badd[n];
}

// ---------------------------------------------------------------------------
// bf16 MFMA GEMM body (m97 structure + XCD super-tiles). NBX=16, NBY=M/128.
// OUTMODE 0: bf16 [m][n]; 1: f32 [m][n]; 2: bf16 transposed [n][m]/[b][n][s]
// ---------------------------------------------------------------------------
template<int K, int OUTMODE, int NBY>
__device__ __forceinline__ void gemm_body(int bid, u16* As, u16* Bs,
                                          const u16* __restrict__ A,
                                          const u16* __restrict__ E,
                                          const float* __restrict__ bias,
                                          void* __restrict__ outp) {
    const int t    = threadIdx.x;
    const int lane = t & 63, wave = t >> 6;
    const int wr   = wave >> 1, wc = wave & 1;
    const int lr   = lane & 15, kg = lane >> 4;
    const int l7   = lr & 7;

    constexpr int SPX = (4 * (NBY / 4)) / 8;
    const int xcd = bid & 7, p = bid >> 3;
    const int st  = xcd * SPX + (p >> 4);
    const int w   = p & 15;
    const int bx  = (st & 3) * 4 + (w & 3);
    const int by  = (st >> 2) * 4 + (w >> 2);
    const int m0  = by * 128;
    const int n0  = bx * 128;

    f32x4 acc[4][4];
#pragma unroll
    for (int i = 0; i < 4; ++i)
#pragma unroll
        for (int j = 0; j < 4; ++j) acc[i][j] = (f32x4){0.f, 0.f, 0.f, 0.f};

    const int arow = wr * 64 + lr;
    const int brow = wc * 64 + lr;

    for (int k0 = 0; k0 < K; k0 += 64) {
#pragma unroll
        for (int c = 0; c < 4; ++c) {
            int idx = t + c * 256;
            int row = idx >> 3, sl = idx & 7;
            int gsl = sl ^ (row & 7);
            gl_lds16(A + (size_t)(m0 + row) * K + k0 + gsl * 8, &As[idx * 8]);
            gl_lds16(E + (size_t)(n0 + row) * K + k0 + gsl * 8, &Bs[idx * 8]);
        }
        __syncthreads();
#pragma unroll
        for (int ks = 0; ks < 2; ++ks) {
            const int slot = (ks * 4 + kg) ^ l7;
            s16x8 av[4], bv[4];
#pragma unroll
            for (int mi = 0; mi < 4; ++mi)
                av[mi] = *(const s16x8*)&As[(arow + mi * 16) * 64 + slot * 8];
#pragma unroll
            for (int ni = 0; ni < 4; ++ni)
                bv[ni] = *(const s16x8*)&Bs[(brow + ni * 16) * 64 + slot * 8];
#pragma unroll
            for (int mi = 0; mi < 4; ++mi)
#pragma unroll
                for (int ni = 0; ni < 4; ++ni)
                    acc[mi][ni] = __builtin_amdgcn_mfma_f32_16x16x32_bf16(
                        av[mi], bv[ni], acc[mi][ni], 0, 0, 0);
        }
        __syncthreads();
    }

#pragma unroll
    for (int ni = 0; ni < 4; ++ni) {
        int n = n0 + wc * 64 + ni * 16 + lr;
        float bvl = bias ? bias[n] : 0.0f;
#pragma unroll
        for (int mi = 0; mi < 4; ++mi) {
#pragma unroll
            for (int r = 0; r < 4; ++r) {
                int m = m0 + wr * 64 + mi * 16 + kg * 4 + r;
                float val = acc[mi][ni][r] + bvl;
                if constexpr (OUTMODE == 0) {
                    ((u16*)outp)[(size_t)m * 2048 + n] = f2bf(val);
                } else if constexpr (OUTMODE == 1) {
                    ((float*)outp)[(size_t)m * 2048 + n] = val;
                } else {
                    int b = m >> 11, s = m & 2047;
                    ((u16*)outp)[((size_t)b * 2048 + n) * 2048 + s] = f2bf(val);
                }
            }
        }
    }
}

template<int K, int OUTMODE, int NBY>
__global__ __launch_bounds__(256) void gemm2(const u16* __restrict__ A,
                                             const u16* __restrict__ E,
                                             const float* __restrict__ bias,
                                             void* __restrict__ outp) {
    __shared__ u16 As[128 * 64];
    __shared__ u16 Bs[128 * 64];
    gemm_body<K, OUTMODE, NBY>(blockIdx.x, As, Bs, A, E, bias, outp);
}

// Layer-A fat kernel: q1 = Z1(ca,cb)=Wfin[ca]*Wint[cb] (256, FIRST) +
// projQ (1024) + projK (1024) + matvec1 tail (512, raw Wfin)
__global__ __launch_bounds__(256) void gemm_fatA(const u16* __restrict__ Aq,
                                                 const u16* __restrict__ Eq,
                                                 const float* __restrict__ bq,
                                                 void* __restrict__ Qt,
                                                 const u16* __restrict__ Ak,
                                                 const u16* __restrict__ Ek,
                                                 const float* __restrict__ bk,
                                                 void* __restrict__ Kt,
                                                 const u16* __restrict__ Xfin,
                                                 const u16* __restrict__ YtInt,
                                                 void* __restrict__ Z1,
                                                 const float* __restrict__ Wfin,
                                                 const float* __restrict__ bint,
                                                 const float* __restrict__ bfin,
                                                 float* __restrict__ bv1) {
    __shared__ u16 As[128 * 64];
    __shared__ u16 Bs[128 * 64];
    int bid = blockIdx.x;
    if (bid < 256) {
        gemm_body<512, 0, 16>(bid, As, Bs, Xfin, YtInt, nullptr, Z1);
    } else if (bid < 1280) {
        gemm_body<512, 2, 64>(bid - 256, As, Bs, Aq, Eq, bq, Qt);
    } else if (bid < 2304) {
        gemm_body<512, 2, 64>(bid - 1280, As, Bs, Ak, Ek, bk, Kt);
    } else {
        mvW_body(bid - 2304, bint, Wfin, bfin, bv1);
    }
}

// ---------------------------------------------------------------------------
// qcomb1: Yt2[cm*512+i][p] = T[cm][p][i] = sum s*Z1[(ca*512+p)][cb*512+i]
// Sign table from e_cb*e_ca = s*e_cm  (W1=Wint is cb, W2=Wfin is ca).
// ---------------------------------------------------------------------------
__global__ __launch_bounds__(256) void qcomb1(const u16* __restrict__ Z1,
                                              u16* __restrict__ Yt2) {
    __shared__ float tile[32][33];
    const int CA[4][4] = {{0,1,2,3},{1,0,3,2},{2,0,1,3},{3,0,2,1}};
    const int CB[4][4] = {{0,1,2,3},{0,1,2,3},{0,2,3,1},{0,3,1,2}};
    const float SG[4][4] = {{1.f,-1.f,-1.f,-1.f},{1.f,1.f,1.f,-1.f},
                            {1.f,1.f,1.f,-1.f},{1.f,1.f,1.f,-1.f}};
    const int cm = blockIdx.z;
    const int p0 = blockIdx.x * 32, i0 = blockIdx.y * 32;
    const int tx = threadIdx.x, ty = threadIdx.y;   // 32 x 8
#pragma unroll
    for (int dy = 0; dy < 32; dy += 8) {
        int p = p0 + ty + dy;
        float acc = 0.f;
#pragma unroll
        for (int q = 0; q < 4; ++q)
            acc += SG[cm][q] * bf2f(Z1[(size_t)(CA[cm][q] * 512 + p) * 2048
                                       + CB[cm][q] * 512 + i0 + tx]);
        tile[ty + dy][tx] = acc;
    }
    __syncthreads();
#pragma unroll
    for (int dy = 0; dy < 32; dy += 8)
        Yt2[((size_t)cm * 512 + i0 + ty + dy) * 512 + p0 + tx]
            = f2bf(tile[tx][ty + dy]);
}

// ---------------------------------------------------------------------------
// In-place FFT (radix-4 head + 3x radix-8), bitrev input -> natural output.
// ---------------------------------------------------------------------------
template<int LH, int OFF>
__device__ __forceinline__ void r8pass(float* re, float* im,
                                       const float2* __restrict__ wt, int t) {
    constexpr int h = 1 << LH;
    __syncthreads();
    const int j  = t & (h - 1);
    const int i0 = ((t >> LH) << (LH + 3)) | j;
    const float2 w = wt[OFF + j];
    const float t2r = w.x * w.x - w.y * w.y;
    const float t2i = 2.f * w.x * w.y;
    const float t1r = t2r * t2r - t2i * t2i;
    const float t1i = 2.f * t2r * t2i;
    const float S = 0.70710678118654752f;
    const float Ac = S * (w.x + w.y);
    const float Bc = S * (w.y - w.x);

    float xr[8], xi[8];
    int p[8];
#pragma unroll
    for (int k = 0; k < 8; ++k) {
        p[k] = PD(i0 + k * h);
        xr[k] = re[p[k]]; xi[k] = im[p[k]];
    }
#pragma unroll
    for (int kp = 0; kp < 8; kp += 2) {
        float tr = t1r * xr[kp + 1] - t1i * xi[kp + 1];
        float ti = t1r * xi[kp + 1] + t1i * xr[kp + 1];
        float ar = xr[kp], ai = xi[kp];
        xr[kp] = ar + tr;     xi[kp] = ai + ti;
        xr[kp + 1] = ar - tr; xi[kp + 1] = ai - ti;
    }
#pragma unroll
    for (int q = 0; q < 2; ++q) {
        int b0 = q * 4;
        {
            float tr = t2r * xr[b0 + 2] - t2i * xi[b0 + 2];
            float ti = t2r * xi[b0 + 2] + t2i * xr[b0 + 2];
            float ar = xr[b0], ai = xi[b0];
            xr[b0] = ar + tr;     xi[b0] = ai + ti;
            xr[b0 + 2] = ar - tr; xi[b0 + 2] = ai - ti;
        }
        {
            float tr = t2i * xr[b0 + 3] + t2r * xi[b0 + 3];
            float ti = t2i * xi[b0 + 3] - t2r * xr[b0 + 3];
            float ar = xr[b0 + 1], ai = xi[b0 + 1];
            xr[b0 + 1] = ar + tr; xi[b0 + 1] = ai + ti;
            xr[b0 + 3] = ar - tr; xi[b0 + 3] = ai - ti;
        }
    }
    {
        float tr = w.x * xr[4] - w.y * xi[4];
        float ti = w.x * xi[4] + w.y * xr[4];
        float ar = xr[0], ai = xi[0];
        xr[0] = ar + tr; xi[0] = ai + ti;
        xr[4] = ar - tr; xi[4] = ai - ti;
    }
    {
        float tr = Ac * xr[5] - Bc * xi[5];
        float ti = Ac * xi[5] + Bc * xr[5];
        float ar = xr[1], ai = xi[1];
        xr[1] = ar + tr; xi[1] = ai + ti;
        xr[5] = ar - tr; xi[5] = ai - ti;
    }
    {
        float tr = w.y * xr[6] + w.x * xi[6];
        float ti = w.y * xi[6] - w.x * xr[6];
        float ar = xr[2], ai = xi[2];
        xr[2] = ar + tr; xi[2] = ai + ti;
        xr[6] = ar - tr; xi[6] = ai - ti;
    }
    {
        float tr = Bc * xr[7] + Ac * xi[7];
        float ti = Bc * xi[7] - Ac * xr[7];
        float ar = xr[3], ai = xi[3];
        xr[3] = ar + tr; xi[3] = ai + ti;
        xr[7] = ar - tr; xi[7] = ai - ti;
    }
#pragma unroll
    for (int k = 0; k < 8; ++k) { re[p[k]] = xr[k]; im[p[k]] = xi[k]; }
}

__device__ void fft2048(float* re, float* im, const float2* __restrict__ wt, int t) {
    __syncthreads();
#pragma unroll
    for (int u = 0; u < 2; ++u) {
        int i0 = (t + u * 256) << 2;
        int p0 = PD(i0);
        float x0r = re[p0],     x0i = im[p0];
        float x1r = re[p0 + 1], x1i = im[p0 + 1];
        float x2r = re[p0 + 2], x2i = im[p0 + 2];
        float x3r = re[p0 + 3], x3i = im[p0 + 3];
        float ar = x0r + x1r, ai = x0i + x1i;
        float br = x0r - x1r, bi = x0i - x1i;
        float cr = x2r + x3r, ci = x2i + x3i;
        float dr = x2r - x3r, di = x2i - x3i;
        re[p0]     = ar + cr; im[p0]     = ai + ci;
        re[p0 + 2] = ar - cr; im[p0 + 2] = ai - ci;
        re[p0 + 1] = br + di; im[p0 + 1] = bi - dr;
        re[p0 + 3] = br - di; im[p0 + 3] = bi + dr;
    }
    r8pass<2, 0>(re, im, wt, t);
    r8pass<5, 4>(re, im, wt, t);
    r8pass<8, 36>(re, im, wt, t);
    __syncthreads();
}

// ---------------------------------------------------------------------------
// Spectral body: 2 channels, packed FFTs; writes WEIGHTS to Wt (aliases Qt).
// ---------------------------------------------------------------------------
__device__ void spectral_body(int sbid, float* zre, float* zim, float2* wt,
                              const u16* __restrict__ Qt,
                              const u16* __restrict__ Kt,
                              u16* __restrict__ Wt,
                              const float* __restrict__ alpha,
                              const float2* __restrict__ gws,
                              const float* __restrict__ gph) {
    const int t  = threadIdx.x;
    const int b  = sbid >> 10;
    const int cp = sbid & 1023;
    const int c0 = cp * 2;
    const size_t base0 = ((size_t)b * 2048 + c0) * 2048;
    const size_t base1 = base0 + 2048;

    for (int i = t; i < 292; i += 256) wt[i] = gws[i];

    float ph[4];
    float PH1r[4], PH1i[4], PH2r[4], PH2i[4];
    float ph24 = 0.f, PH24_1 = 0.f, PH24_2 = 0.f;

#pragma unroll
    for (int ch = 0; ch < 2; ++ch) {
        const size_t base = ch ? base1 : base0;
        const u16* Qp = Qt + base;
        const u16* Kp = Kt + base;
        __syncthreads();
#pragma unroll
        for (int u = 0; u < 8; ++u) {
            int s = t + u * 256;
            int r = __brev((unsigned)s) >> 21;
            zre[PD(r)] = bf2f(Qp[s]);
            zim[PD(r)] = bf2f(Kp[s]);
        }
        fft2048(zre, zim, wt, t);
        const float ac = alpha[c0 + ch];
#pragma unroll
        for (int u = 0; u < 4; ++u) {
            int k = t + u * 256;
            int m = (2048 - k) & 2047;
            float ar = zre[PD(k)], ai = zim[PD(k)];
            float br = zre[PD(m)], bi = zim[PD(m)];
            float qr = 0.5f * (ar + br), qi = 0.5f * (ai - bi);
            float kr = 0.5f * (ai + bi), ki = 0.5f * (br - ar);
            float cr = qr * kr + qi * ki;
            float ci = qi * kr - qr * ki;
            if (ch == 0) ph[u] = gph[min(k, 2048 - k)];
            float fr, fi;
            __sincosf(ph[u] * ac, &fi, &fr);
            float Pkr = cr * fr - ci * fi, Pki = cr * fi + ci * fr;
            float qr2 = 0.5f * (br + ar), qi2 = 0.5f * (bi - ai);
            float kr2 = 0.5f * (bi + ai), ki2 = 0.5f * (ar - br);
            float cr2 = qr2 * kr2 + qi2 * ki2;
            float ci2 = qi2 * kr2 - qr2 * ki2;
            float Pmr = cr2 * fr - ci2 * fi, Pmi = cr2 * fi + ci2 * fr;
            float hr = 0.5f * (Pkr + Pmr), hi = 0.5f * (Pki - Pmi);
            if (ch == 0) { PH1r[u] = hr; PH1i[u] = hi; }
            else         { PH2r[u] = hr; PH2i[u] = hi; }
        }
        if (t == 0) {
            float ar = zre[PD(1024)], ai = zim[PD(1024)];
            float cr = ar * ai;
            if (ch == 0) ph24 = gph[1024];
            float fr, fi;
            __sincosf(ph24 * ac, &fi, &fr);
            if (ch == 0) PH24_1 = cr * fr; else PH24_2 = cr * fr;
        }
    }

    __syncthreads();
#pragma unroll
    for (int u = 0; u < 4; ++u) {
        int k = t + u * 256;
        int m = (2048 - k) & 2047;
        int rk = __brev((unsigned)k) >> 21;
        int rm = __brev((unsigned)m) >> 21;
        zre[PD(rk)] = PH1r[u] - PH2i[u];
        zim[PD(rk)] = PH1i[u] + PH2r[u];
        zre[PD(rm)] = PH1r[u] + PH2i[u];
        zim[PD(rm)] = PH2r[u] - PH1i[u];
    }
    if (t == 0) {
        zre[PD(1)] = PH24_1;
        zim[PD(1)] = PH24_2;
    }
    fft2048(zre, zim, wt, t);

#pragma unroll
    for (int u = 0; u < 8; ++u) {
        int s = t + u * 256;
        int j = (2048 - s) & 2047;
        Wt[base0 + s] = f2bf(zre[PD(j)] * (1.0f / 2048.0f));
        Wt[base1 + s] = f2bf(zim[PD(j)] * (1.0f / 2048.0f));
    }
}

// Layer-B fat kernel: q2 = Z2(ca,cb)=Wout[ca]*T[cb] (256, FIRST) +
// spectral (4096) + projV (1024) 4:1 + matvec2 tail (512, raw Wout).
__global__ __launch_bounds__(256) void fat_specv(const u16* __restrict__ Qt,
                                                 const u16* __restrict__ Kt,
                                                 u16* __restrict__ Wt,
                                                 const float* __restrict__ alpha,
                                                 const float2* __restrict__ gws,
                                                 const float* __restrict__ gph,
                                                 const u16* __restrict__ Av,
                                                 const u16* __restrict__ Ev,
                                                 const float* __restrict__ bvb,
                                                 void* __restrict__ Vt,
                                                 const u16* __restrict__ Xout,
                                                 const u16* __restrict__ Yt2,
                                                 void* __restrict__ Z2,
                                                 const float* __restrict__ Wout,
                                                 const float* __restrict__ bv1,
                                                 const float* __restrict__ bout,
                                                 float* __restrict__ bv2) {
    __shared__ __align__(16) char smem[32768];
    int bid = blockIdx.x;
    if (bid < 256) {
        gemm_body<512, 0, 16>(bid, (u16*)smem, (u16*)(smem + 16384),
                              Xout, Yt2, nullptr, Z2);
        return;
    }
    if (bid >= 5376) {
        mvW_body(bid - 5376, bv1, Wout, bout, bv2);
        return;
    }
    bid -= 256;
    if (bid % 5 == 4) {
        gemm_body<512, 2, 64>(bid / 5, (u16*)smem, (u16*)(smem + 16384),
                              Av, Ev, bvb, Vt);
    } else {
        int sbid = (bid / 5) * 4 + (bid % 5);
        spectral_body(sbid, (float*)smem, (float*)(smem + 8960),
                      (float2*)(smem + 17920), Qt, Kt, Wt, alpha, gws, gph);
    }
}

// ---------------------------------------------------------------------------
// fat_post: qcomb2 (Z2 -> Ecomb, 1024 blocks) + transpose_mul (4096 blocks).
// ---------------------------------------------------------------------------
__device__ __forceinline__ void qcomb2_body(int blk, const u16* __restrict__ Z2,
                                            u16* __restrict__ Ecomb) {
    int id = blk * 256 + threadIdx.x;       // < 262144
    int q = id >> 9, i = id & 511;
    float z[4][4];
#pragma unroll
    for (int ca = 0; ca < 4; ++ca)
#pragma unroll
        for (int cb = 0; cb < 4; ++cb)
            z[ca][cb] = bf2f(Z2[(size_t)(ca * 512 + q) * 2048 + cb * 512 + i]);
    float wc[4];
    wc[0] = z[0][0] - z[1][1] - z[2][2] - z[3][3];
    wc[1] = z[1][0] + z[0][1] + z[3][2] - z[2][3];
    wc[2] = z[2][0] + z[0][2] + z[1][3] - z[3][1];
    wc[3] = z[3][0] + z[0][3] + z[2][1] - z[1][2];
#pragma unroll
    for (int c = 0; c < 4; ++c) {
        u16x4 row;
#pragma unroll
        for (int cp = 0; cp < 4; ++cp) {
            int qmv; float qsv; hamilton(c, cp, qmv, qsv);
            row[cp] = f2bf(qsv * wc[qmv]);
        }
        *(u16x4*)&Ecomb[(size_t)(4 * q + c) * 2048 + 4 * i] = row;
    }
}

__device__ __forceinline__ void tmul_body(int blk, const u16* __restrict__ W,
                                          const u16* __restrict__ V,
                                          u16* __restrict__ out, u16* tile) {
    // tile: [64][70] u16
    const int b  = blk >> 10;
    const int rem = blk & 1023;
    const int c0 = (rem & 31) * 64, s0 = (rem >> 5) * 64;
    const int t  = threadIdx.x;
    const int g  = (t & 15) * 4;
    const int rb = t >> 4;
#pragma unroll
    for (int r = 0; r < 4; ++r) {
        int c = rb + 16 * r;
        size_t idx = ((size_t)b * 2048 + c0 + c) * 2048 + s0 + g;
        u16x4 wv = *(const u16x4*)&W[idx];
        u16x4 vv = *(const u16x4*)&V[idx];
#pragma unroll
        for (int j = 0; j < 4; ++j)
            tile[c * 70 + g + j] = f2bf(bf2f(wv[j]) * bf2f(vv[j]));
    }
    __syncthreads();
#pragma unroll
    for (int r = 0; r < 4; ++r) {
        int s = rb + 16 * r;
        u16x4 o;
#pragma unroll
        for (int j = 0; j < 4; ++j) o[j] = tile[(g + j) * 70 + s];
        *(u16x4*)&out[((size_t)b * 2048 + s0 + s) * 2048 + c0 + g] = o;
    }
}

__global__ __launch_bounds__(256) void fat_post(const u16* __restrict__ Z2,
                                                u16* __restrict__ Ecomb,
                                                const u16* __restrict__ W,
                                                const u16* __restrict__ V,
                                                u16* __restrict__ attn) {
    __shared__ u16 tile[64 * 70];
    int bid = blockIdx.x;
    if (bid < 1024) qcomb2_body(bid, Z2, Ecomb);
    else            tmul_body(bid - 1024, W, V, attn, tile);
}

// ---------------------------------------------------------------------------
extern "C" void kernel_launch(void* const* d_in, const int* in_sizes, int n_in,
                              void* d_out, int out_size, void* d_ws, size_t ws_size,
                              hipStream_t stream) {
    const float* query = (const float*)d_in[0];
    const float* key   = (const float*)d_in[1];
    const float* value = (const float*)d_in[2];
    const float* Wq    = (const float*)d_in[3];
    const float* bq    = (const float*)d_in[4];
    const float* Wk    = (const float*)d_in[5];
    const float* bk    = (const float*)d_in[6];
    const float* Wv    = (const float*)d_in[7];
    const float* bv    = (const float*)d_in[8];
    const float* alpha = (const float*)d_in[9];
    const float* Wint  = (const float*)d_in[10];
    const float* bint  = (const float*)d_in[11];
    const float* Wfin  = (const float*)d_in[12];
    const float* bfin  = (const float*)d_in[13];
    const float* Wout  = (const float*)d_in[14];
    const float* bout  = (const float*)d_in[15];

    char* ws = (char*)d_ws;
    size_t off = 0;
    auto alloc = [&](size_t bytes) -> void* {
        void* p = ws + off;
        off += (bytes + 255) & ~(size_t)255;
        return p;
    };
    u16* Eq    = (u16*)alloc((size_t)2048 * 512 * 2);
    u16* Ek    = (u16*)alloc((size_t)2048 * 512 * 2);
    u16* Ev    = (u16*)alloc((size_t)2048 * 512 * 2);
    u16* Xfin  = (u16*)alloc((size_t)2048 * 512 * 2);
    u16* Xout  = (u16*)alloc((size_t)2048 * 512 * 2);
    u16* YtInt = (u16*)alloc((size_t)2048 * 512 * 2);
    u16* Yt2   = (u16*)alloc((size_t)2048 * 512 * 2);
    u16* Z1    = (u16*)alloc((size_t)2048 * 2048 * 2);
    u16* Z2    = (u16*)alloc((size_t)2048 * 2048 * 2);
    u16* Ecomb = (u16*)alloc((size_t)2048 * 2048 * 2);
    u16* Qt    = (u16*)alloc((size_t)4 * 2048 * 2048 * 2);
    u16* Kt    = (u16*)alloc((size_t)4 * 2048 * 2048 * 2);
    u16* Vt    = (u16*)alloc((size_t)4 * 2048 * 2048 * 2);
    u16* attn  = (u16*)alloc((size_t)8192 * 2048 * 2);
    float2* gws = (float2*)alloc(292 * 8);
    float*  pht = (float*)alloc(1025 * 4);
    float*  bv1 = (float*)alloc(2048 * 4);
    float*  bv2 = (float*)alloc(2048 * 4);
    u16* Wt = Qt;   // spectral writes weights in place over Qt
    u16* Aq = attn;
    u16* Ak = attn + (size_t)8192 * 512;
    u16* Av = attn + (size_t)8192 * 1024;

    // fused prep: cvt x3, E<9> x3, Xfin, Xout, YtInt, tables
    fat_prep<<<23557, 256, 0, stream>>>(query, key, value, Aq,
                                        Wq, Wk, Wv, Eq, Ek, Ev,
                                        Wint, Wfin, Wout, Xfin, Xout, YtInt,
                                        gws, pht);

    // Layer A: q1 (first) + projQ + projK + matvec1 tail
    gemm_fatA<<<2816, 256, 0, stream>>>(Aq, Eq, bq, Qt, Ak, Ek, bk, Kt,
                                        Xfin, YtInt, Z1, Wfin, bint, bfin, bv1);

    // quaternion sign-combine 1: Z1 -> Yt2 (T transposed per comp)
    qcomb1<<<dim3(16, 16, 4), dim3(32, 8), 0, stream>>>(Z1, Yt2);

    // Layer B: q2 (first) + spectral (in-place over Qt) + projV + matvec2
    fat_specv<<<5888, 256, 0, stream>>>(Qt, Kt, Wt, alpha, gws, pht,
                                        Av, Ev, bv, Vt, Xout, Yt2, Z2,
                                        Wout, bv1, bout, bv2);

    // qcomb2 (Z2 -> Ecomb) + transpose_mul (attn = (W.*V)^T), one grid
    fat_post<<<5120, 256, 0, stream>>>(Z2, Ecomb, Wt, Vt, attn);

    // single fused trailing linear
    gemm2<2048, 1, 64><<<1024, 256, 0, stream>>>(attn, Ecomb, bv2, (float*)d_out);
}

// Round 23
// 306.371 us; speedup vs baseline: 1.1843x; 1.0021x over previous
//
#include <hip/hip_runtime.h>
#include <hip/hip_bf16.h>
#include <cstdint>

typedef unsigned short u16;
typedef u16  u16x4 __attribute__((ext_vector_type(4)));
typedef u16  u16x8 __attribute__((ext_vector_type(8)));
typedef short s16x8 __attribute__((ext_vector_type(8)));
typedef float f32x4 __attribute__((ext_vector_type(4)));

#define PI_F 3.14159265358979323846f
#define PD(i) ((i) + 3 * ((i) >> 5))

static __device__ __forceinline__ u16 f2bf(float f) {
    union { float f; unsigned u; } v; v.f = f;
    unsigned r = v.u + 0x7fffu + ((v.u >> 16) & 1u);
    return (u16)(r >> 16);
}
static __device__ __forceinline__ float bf2f(u16 h) {
    union { unsigned u; float f; } v; v.u = ((unsigned)h) << 16;
    return v.f;
}

__device__ __forceinline__ void gl_lds16(const u16* g, u16* l) {
    __builtin_amdgcn_global_load_lds(
        (const __attribute__((address_space(1))) unsigned int*)g,
        (__attribute__((address_space(3))) unsigned int*)l, 16, 0, 0);
}

// ---------------------------------------------------------------------------
// Fused prep: cvt x3 + E<9> x3 + Xfin/Xout (plain cvt of W) + YtInt + tables.
// Ranges: [0,6144) cvt | [6144,18432) E<9> | [18432,18944) Xfin |
// [18944,19456) Xout | [19456,23552) YtInt | [23552,23557) tabs.
// ---------------------------------------------------------------------------
__device__ __forceinline__ void cvt_body(int blk, const float* __restrict__ in,
                                         u16* __restrict__ o) {
    int i = blk * 256 + threadIdx.x;
    float4 a = ((const float4*)in)[2 * i];
    float4 b = ((const float4*)in)[2 * i + 1];
    u16x8 vv;
    vv[0] = f2bf(a.x); vv[1] = f2bf(a.y); vv[2] = f2bf(a.z); vv[3] = f2bf(a.w);
    vv[4] = f2bf(b.x); vv[5] = f2bf(b.y); vv[6] = f2bf(b.z); vv[7] = f2bf(b.w);
    ((u16x8*)o)[i] = vv;
}

__device__ __forceinline__ void hamilton(int c, int cp, int& qmv, float& qsv) {
    const int   qm[4][4] = {{0,1,2,3},{1,0,3,2},{2,3,0,1},{3,2,1,0}};
    const float qs[4][4] = {{1.f,-1.f,-1.f,-1.f},{1.f,1.f,1.f,-1.f},
                            {1.f,-1.f,1.f,1.f},{1.f,1.f,-1.f,1.f}};
    qmv = qm[c][cp]; qsv = qs[c][cp];
}

template<int LOGK>
__device__ __forceinline__ void e3_body(int blk, const float* __restrict__ W,
                                        u16* __restrict__ E) {
    const int K = 1 << LOGK;
    int idx = blk * 256 + threadIdx.x;
    int n = idx >> LOGK, k = idx & (K - 1);
    int o = n >> 2, c = n & 3, i = k >> 2, cp = k & 3;
    int qmv; float qsv; hamilton(c, cp, qmv, qsv);
    int in_q = K >> 2;
    float w = W[(size_t)qmv * 512 * in_q + (size_t)o * in_q + i] * qsv;
    E[idx] = f2bf(w);
}

// YtInt[cb*512+i][o] = Wint[cb][o][i]  (per-comp transpose)
__device__ __forceinline__ void ytr_body(int blk, const float* __restrict__ W,
                                         u16* __restrict__ YT) {
    int b = blk * 256 + threadIdx.x;          // < 1048576
    int row = b >> 9, o = b & 511;
    int cb = row >> 9, i = row & 511;
    YT[b] = f2bf(W[((size_t)cb * 512 + o) * 512 + i]);
}

// r8 twiddle tables + phases
__device__ __forceinline__ void tabs_body(int blk, float2* __restrict__ gws,
                                          float* __restrict__ ph) {
    int i = blk * 256 + threadIdx.x;
    if (i < 292) {
        int off, denom;
        if (i < 4)       { off = 0;  denom = 16;   }
        else if (i < 36) { off = 4;  denom = 128;  }
        else             { off = 36; denom = 1024; }
        float a = (-PI_F) * (float)(i - off) / (float)denom;
        gws[i] = make_float2(cosf(a), sinf(a));
    }
    if (i <= 1024) {
        ph[i] = atanf(logf((float)i * (1.0f / 2048.0f) + 1e-6f));
    }
}

__global__ __launch_bounds__(256) void fat_prep(
        const float* __restrict__ query, const float* __restrict__ key,
        const float* __restrict__ value, u16* __restrict__ Acvt,
        const float* __restrict__ Wq, const float* __restrict__ Wk,
        const float* __restrict__ Wv, u16* __restrict__ Eq,
        u16* __restrict__ Ek, u16* __restrict__ Ev,
        const float* __restrict__ Wint, const float* __restrict__ Wfin,
        const float* __restrict__ Wout, u16* __restrict__ Xfin,
        u16* __restrict__ Xout, u16* __restrict__ YtInt,
        float2* __restrict__ gws, float* __restrict__ pht) {
    int b = blockIdx.x;
    if (b < 6144) {
        int ten = b >> 11, r = b & 2047;
        const float* in = (ten == 0) ? query : (ten == 1) ? key : value;
        cvt_body(r, in, Acvt + (size_t)ten * 8192 * 512);
    } else if (b < 18432) {
        int rb = b - 6144;
        int y = rb >> 12, r = rb & 4095;
        e3_body<9>(r, (y == 0) ? Wq : (y == 1) ? Wk : Wv,
                   (y == 0) ? Eq : (y == 1) ? Ek : Ev);
    } else if (b < 18944) {
        cvt_body(b - 18432, Wfin, Xfin);      // Xfin[ca*512+p][o] = Wfin flat
    } else if (b < 19456) {
        cvt_body(b - 18944, Wout, Xout);
    } else if (b < 23552) {
        ytr_body(b - 19456, Wint, YtInt);
    } else {
        tabs_body(b - 23552, gws, pht);
    }
}

// ---------------------------------------------------------------------------
// Bias matvec on raw quaternion weights: out[n] = sum_k v[k]*E(W)[n][k]+badd
// E(W)[4o+c][4i+cp] = qs[c][cp]*W[qm[c][cp]][o][i]; cp = lane&3 is constant.
// ---------------------------------------------------------------------------
__device__ __forceinline__ void mvW_body(int blk, const float* __restrict__ v,
                                         const float* __restrict__ W,
                                         const float* __restrict__ badd,
                                         float* __restrict__ out) {
    int n    = (blk * 256 + threadIdx.x) >> 6;
    int lane = threadIdx.x & 63;
    if (n >= 2048) return;
    int o = n >> 2, c = n & 3;
    int cp = lane & 3;
    int qmv; float qsv; hamilton(c, cp, qmv, qsv);
    const float* Wrow = W + ((size_t)qmv * 512 + o) * 512;
    float s = 0.f;
    for (int k = lane; k < 2048; k += 64) s += v[k] * Wrow[k >> 2];
    s *= qsv;
#pragma unroll
    for (int off = 32; off; off >>= 1) s += __shfl_down(s, off, 64);
    if (lane == 0) out[n] = s + badd[n];
}

// ---------------------------------------------------------------------------
// bf16 MFMA GEMM body (m97 structure + XCD super-tiles). NBX=16, NBY=M/128.
// OUTMODE 0: bf16 [m][n]; 1: f32 [m][n]; 2: bf16 transposed [n][m]/[b][n][s]
// ---------------------------------------------------------------------------
template<int K, int OUTMODE, int NBY>
__device__ __forceinline__ void gemm_body(int bid, u16* As, u16* Bs,
                                          const u16* __restrict__ A,
                                          const u16* __restrict__ E,
                                          const float* __restrict__ bias,
                                          void* __restrict__ outp) {
    const int t    = threadIdx.x;
    const int lane = t & 63, wave = t >> 6;
    const int wr   = wave >> 1, wc = wave & 1;
    const int lr   = lane & 15, kg = lane >> 4;
    const int l7   = lr & 7;

    constexpr int SPX = (4 * (NBY / 4)) / 8;
    const int xcd = bid & 7, p = bid >> 3;
    const int st  = xcd * SPX + (p >> 4);
    const int w   = p & 15;
    const int bx  = (st & 3) * 4 + (w & 3);
    const int by  = (st >> 2) * 4 + (w >> 2);
    const int m0  = by * 128;
    const int n0  = bx * 128;

    f32x4 acc[4][4];
#pragma unroll
    for (int i = 0; i < 4; ++i)
#pragma unroll
        for (int j = 0; j < 4; ++j) acc[i][j] = (f32x4){0.f, 0.f, 0.f, 0.f};

    const int arow = wr * 64 + lr;
    const int brow = wc * 64 + lr;

    for (int k0 = 0; k0 < K; k0 += 64) {
#pragma unroll
        for (int c = 0; c < 4; ++c) {
            int idx = t + c * 256;
            int row = idx >> 3, sl = idx & 7;
            int gsl = sl ^ (row & 7);
            gl_lds16(A + (size_t)(m0 + row) * K + k0 + gsl * 8, &As[idx * 8]);
            gl_lds16(E + (size_t)(n0 + row) * K + k0 + gsl * 8, &Bs[idx * 8]);
        }
        __syncthreads();
#pragma unroll
        for (int ks = 0; ks < 2; ++ks) {
            const int slot = (ks * 4 + kg) ^ l7;
            s16x8 av[4], bv[4];
#pragma unroll
            for (int mi = 0; mi < 4; ++mi)
                av[mi] = *(const s16x8*)&As[(arow + mi * 16) * 64 + slot * 8];
#pragma unroll
            for (int ni = 0; ni < 4; ++ni)
                bv[ni] = *(const s16x8*)&Bs[(brow + ni * 16) * 64 + slot * 8];
#pragma unroll
            for (int mi = 0; mi < 4; ++mi)
#pragma unroll
                for (int ni = 0; ni < 4; ++ni)
                    acc[mi][ni] = __builtin_amdgcn_mfma_f32_16x16x32_bf16(
                        av[mi], bv[ni], acc[mi][ni], 0, 0, 0);
        }
        __syncthreads();
    }

#pragma unroll
    for (int ni = 0; ni < 4; ++ni) {
        int n = n0 + wc * 64 + ni * 16 + lr;
        float bvl = bias ? bias[n] : 0.0f;
#pragma unroll
        for (int mi = 0; mi < 4; ++mi) {
#pragma unroll
            for (int r = 0; r < 4; ++r) {
                int m = m0 + wr * 64 + mi * 16 + kg * 4 + r;
                float val = acc[mi][ni][r] + bvl;
                if constexpr (OUTMODE == 0) {
                    ((u16*)outp)[(size_t)m * 2048 + n] = f2bf(val);
                } else if constexpr (OUTMODE == 1) {
                    ((float*)outp)[(size_t)m * 2048 + n] = val;
                } else {
                    int b = m >> 11, s = m & 2047;
                    ((u16*)outp)[((size_t)b * 2048 + n) * 2048 + s] = f2bf(val);
                }
            }
        }
    }
}

template<int K, int OUTMODE, int NBY>
__global__ __launch_bounds__(256) void gemm2(const u16* __restrict__ A,
                                             const u16* __restrict__ E,
                                             const float* __restrict__ bias,
                                             void* __restrict__ outp) {
    __shared__ u16 As[128 * 64];
    __shared__ u16 Bs[128 * 64];
    gemm_body<K, OUTMODE, NBY>(blockIdx.x, As, Bs, A, E, bias, outp);
}

// Layer-A fat kernel: q1 = Z1(ca,cb)=Wfin[ca]*Wint[cb] (256, FIRST) +
// projQ (1024) + projK (1024) + matvec1 tail (512, raw Wfin)
__global__ __launch_bounds__(256) void gemm_fatA(const u16* __restrict__ Aq,
                                                 const u16* __restrict__ Eq,
                                                 const float* __restrict__ bq,
                                                 void* __restrict__ Qt,
                                                 const u16* __restrict__ Ak,
                                                 const u16* __restrict__ Ek,
                                                 const float* __restrict__ bk,
                                                 void* __restrict__ Kt,
                                                 const u16* __restrict__ Xfin,
                                                 const u16* __restrict__ YtInt,
                                                 void* __restrict__ Z1,
                                                 const float* __restrict__ Wfin,
                                                 const float* __restrict__ bint,
                                                 const float* __restrict__ bfin,
                                                 float* __restrict__ bv1) {
    __shared__ u16 As[128 * 64];
    __shared__ u16 Bs[128 * 64];
    int bid = blockIdx.x;
    if (bid < 256) {
        gemm_body<512, 0, 16>(bid, As, Bs, Xfin, YtInt, nullptr, Z1);
    } else if (bid < 1280) {
        gemm_body<512, 2, 64>(bid - 256, As, Bs, Aq, Eq, bq, Qt);
    } else if (bid < 2304) {
        gemm_body<512, 2, 64>(bid - 1280, As, Bs, Ak, Ek, bk, Kt);
    } else {
        mvW_body(bid - 2304, bint, Wfin, bfin, bv1);
    }
}

// ---------------------------------------------------------------------------
// qcomb1: Yt2[cm*512+i][p] = T[cm][p][i] = sum s*Z1[(ca*512+p)][cb*512+i]
// Sign table from e_cb*e_ca = s*e_cm  (W1=Wint is cb, W2=Wfin is ca).
// ---------------------------------------------------------------------------
__global__ __launch_bounds__(256) void qcomb1(const u16* __restrict__ Z1,
                                              u16* __restrict__ Yt2) {
    __shared__ float tile[32][33];
    const int CA[4][4] = {{0,1,2,3},{1,0,3,2},{2,0,1,3},{3,0,2,1}};
    const int CB[4][4] = {{0,1,2,3},{0,1,2,3},{0,2,3,1},{0,3,1,2}};
    const float SG[4][4] = {{1.f,-1.f,-1.f,-1.f},{1.f,1.f,1.f,-1.f},
                            {1.f,1.f,1.f,-1.f},{1.f,1.f,1.f,-1.f}};
    const int cm = blockIdx.z;
    const int p0 = blockIdx.x * 32, i0 = blockIdx.y * 32;
    const int tx = threadIdx.x, ty = threadIdx.y;   // 32 x 8
#pragma unroll
    for (int dy = 0; dy < 32; dy += 8) {
        int p = p0 + ty + dy;
        float acc = 0.f;
#pragma unroll
        for (int q = 0; q < 4; ++q)
            acc += SG[cm][q] * bf2f(Z1[(size_t)(CA[cm][q] * 512 + p) * 2048
                                       + CB[cm][q] * 512 + i0 + tx]);
        tile[ty + dy][tx] = acc;
    }
    __syncthreads();
#pragma unroll
    for (int dy = 0; dy < 32; dy += 8)
        Yt2[((size_t)cm * 512 + i0 + ty + dy) * 512 + p0 + tx]
            = f2bf(tile[tx][ty + dy]);
}

// ---------------------------------------------------------------------------
// In-place FFT (radix-4 head + 3x radix-8), bitrev input -> natural output.
// ---------------------------------------------------------------------------
template<int LH, int OFF>
__device__ __forceinline__ void r8pass(float* re, float* im,
                                       const float2* __restrict__ wt, int t) {
    constexpr int h = 1 << LH;
    __syncthreads();
    const int j  = t & (h - 1);
    const int i0 = ((t >> LH) << (LH + 3)) | j;
    const float2 w = wt[OFF + j];
    const float t2r = w.x * w.x - w.y * w.y;
    const float t2i = 2.f * w.x * w.y;
    const float t1r = t2r * t2r - t2i * t2i;
    const float t1i = 2.f * t2r * t2i;
    const float S = 0.70710678118654752f;
    const float Ac = S * (w.x + w.y);
    const float Bc = S * (w.y - w.x);

    float xr[8], xi[8];
    int p[8];
#pragma unroll
    for (int k = 0; k < 8; ++k) {
        p[k] = PD(i0 + k * h);
        xr[k] = re[p[k]]; xi[k] = im[p[k]];
    }
#pragma unroll
    for (int kp = 0; kp < 8; kp += 2) {
        float tr = t1r * xr[kp + 1] - t1i * xi[kp + 1];
        float ti = t1r * xi[kp + 1] + t1i * xr[kp + 1];
        float ar = xr[kp], ai = xi[kp];
        xr[kp] = ar + tr;     xi[kp] = ai + ti;
        xr[kp + 1] = ar - tr; xi[kp + 1] = ai - ti;
    }
#pragma unroll
    for (int q = 0; q < 2; ++q) {
        int b0 = q * 4;
        {
            float tr = t2r * xr[b0 + 2] - t2i * xi[b0 + 2];
            float ti = t2r * xi[b0 + 2] + t2i * xr[b0 + 2];
            float ar = xr[b0], ai = xi[b0];
            xr[b0] = ar + tr;     xi[b0] = ai + ti;
            xr[b0 + 2] = ar - tr; xi[b0 + 2] = ai - ti;
        }
        {
            float tr = t2i * xr[b0 + 3] + t2r * xi[b0 + 3];
            float ti = t2i * xi[b0 + 3] - t2r * xr[b0 + 3];
            float ar = xr[b0 + 1], ai = xi[b0 + 1];
            xr[b0 + 1] = ar + tr; xi[b0 + 1] = ai + ti;
            xr[b0 + 3] = ar - tr; xi[b0 + 3] = ai - ti;
        }
    }
    {
        float tr = w.x * xr[4] - w.y * xi[4];
        float ti = w.x * xi[4] + w.y * xr[4];
        float ar = xr[0], ai = xi[0];
        xr[0] = ar + tr; xi[0] = ai + ti;
        xr[4] = ar - tr; xi[4] = ai - ti;
    }
    {
        float tr = Ac * xr[5] - Bc * xi[5];
        float ti = Ac * xi[5] + Bc * xr[5];
        float ar = xr[1], ai = xi[1];
        xr[1] = ar + tr; xi[1] = ai + ti;
        xr[5] = ar - tr; xi[5] = ai - ti;
    }
    {
        float tr = w.y * xr[6] + w.x * xi[6];
        float ti = w.y * xi[6] - w.x * xr[6];
        float ar = xr[2], ai = xi[2];
        xr[2] = ar + tr; xi[2] = ai + ti;
        xr[6] = ar - tr; xi[6] = ai - ti;
    }
    {
        float tr = Bc * xr[7] + Ac * xi[7];
        float ti = Bc * xi[7] - Ac * xr[7];
        float ar = xr[3], ai = xi[3];
        xr[3] = ar + tr; xi[3] = ai + ti;
        xr[7] = ar - tr; xi[7] = ai - ti;
    }
#pragma unroll
    for (int k = 0; k < 8; ++k) { re[p[k]] = xr[k]; im[p[k]] = xi[k]; }
}

__device__ void fft2048(float* re, float* im, const float2* __restrict__ wt, int t) {
    __syncthreads();
#pragma unroll
    for (int u = 0; u < 2; ++u) {
        int i0 = (t + u * 256) << 2;
        int p0 = PD(i0);
        float x0r = re[p0],     x0i = im[p0];
        float x1r = re[p0 + 1], x1i = im[p0 + 1];
        float x2r = re[p0 + 2], x2i = im[p0 + 2];
        float x3r = re[p0 + 3], x3i = im[p0 + 3];
        float ar = x0r + x1r, ai = x0i + x1i;
        float br = x0r - x1r, bi = x0i - x1i;
        float cr = x2r + x3r, ci = x2i + x3i;
        float dr = x2r - x3r, di = x2i - x3i;
        re[p0]     = ar + cr; im[p0]     = ai + ci;
        re[p0 + 2] = ar - cr; im[p0 + 2] = ai - ci;
        re[p0 + 1] = br + di; im[p0 + 1] = bi - dr;
        re[p0 + 3] = br - di; im[p0 + 3] = bi + dr;
    }
    r8pass<2, 0>(re, im, wt, t);
    r8pass<5, 4>(re, im, wt, t);
    r8pass<8, 36>(re, im, wt, t);
    __syncthreads();
}

// ---------------------------------------------------------------------------
// Spectral body: 2 channels, packed FFTs; writes WEIGHTS to Wt (aliases Qt).
// ---------------------------------------------------------------------------
__device__ void spectral_body(int sbid, float* zre, float* zim, float2* wt,
                              const u16* __restrict__ Qt,
                              const u16* __restrict__ Kt,
                              u16* __restrict__ Wt,
                              const float* __restrict__ alpha,
                              const float2* __restrict__ gws,
                              const float* __restrict__ gph) {
    const int t  = threadIdx.x;
    const int b  = sbid >> 10;
    const int cp = sbid & 1023;
    const int c0 = cp * 2;
    const size_t base0 = ((size_t)b * 2048 + c0) * 2048;
    const size_t base1 = base0 + 2048;

    for (int i = t; i < 292; i += 256) wt[i] = gws[i];

    float ph[4];
    float PH1r[4], PH1i[4], PH2r[4], PH2i[4];
    float ph24 = 0.f, PH24_1 = 0.f, PH24_2 = 0.f;

#pragma unroll
    for (int ch = 0; ch < 2; ++ch) {
        const size_t base = ch ? base1 : base0;
        const u16* Qp = Qt + base;
        const u16* Kp = Kt + base;
        __syncthreads();
#pragma unroll
        for (int u = 0; u < 8; ++u) {
            int s = t + u * 256;
            int r = __brev((unsigned)s) >> 21;
            zre[PD(r)] = bf2f(Qp[s]);
            zim[PD(r)] = bf2f(Kp[s]);
        }
        fft2048(zre, zim, wt, t);
        const float ac = alpha[c0 + ch];
#pragma unroll
        for (int u = 0; u < 4; ++u) {
            int k = t + u * 256;
            int m = (2048 - k) & 2047;
            float ar = zre[PD(k)], ai = zim[PD(k)];
            float br = zre[PD(m)], bi = zim[PD(m)];
            float qr = 0.5f * (ar + br), qi = 0.5f * (ai - bi);
            float kr = 0.5f * (ai + bi), ki = 0.5f * (br - ar);
            float cr = qr * kr + qi * ki;
            float ci = qi * kr - qr * ki;
            if (ch == 0) ph[u] = gph[min(k, 2048 - k)];
            float fr, fi;
            __sincosf(ph[u] * ac, &fi, &fr);
            float Pkr = cr * fr - ci * fi, Pki = cr * fi + ci * fr;
            float qr2 = 0.5f * (br + ar), qi2 = 0.5f * (bi - ai);
            float kr2 = 0.5f * (bi + ai), ki2 = 0.5f * (ar - br);
            float cr2 = qr2 * kr2 + qi2 * ki2;
            float ci2 = qi2 * kr2 - qr2 * ki2;
            float Pmr = cr2 * fr - ci2 * fi, Pmi = cr2 * fi + ci2 * fr;
            float hr = 0.5f * (Pkr + Pmr), hi = 0.5f * (Pki - Pmi);
            if (ch == 0) { PH1r[u] = hr; PH1i[u] = hi; }
            else         { PH2r[u] = hr; PH2i[u] = hi; }
        }
        if (t == 0) {
            float ar = zre[PD(1024)], ai = zim[PD(1024)];
            float cr = ar * ai;
            if (ch == 0) ph24 = gph[1024];
            float fr, fi;
            __sincosf(ph24 * ac, &fi, &fr);
            if (ch == 0) PH24_1 = cr * fr; else PH24_2 = cr * fr;
        }
    }

    __syncthreads();
#pragma unroll
    for (int u = 0; u < 4; ++u) {
        int k = t + u * 256;
        int m = (2048 - k) & 2047;
        int rk = __brev((unsigned)k) >> 21;
        int rm = __brev((unsigned)m) >> 21;
        zre[PD(rk)] = PH1r[u] - PH2i[u];
        zim[PD(rk)] = PH1i[u] + PH2r[u];
        zre[PD(rm)] = PH1r[u] + PH2i[u];
        zim[PD(rm)] = PH2r[u] - PH1i[u];
    }
    if (t == 0) {
        zre[PD(1)] = PH24_1;
        zim[PD(1)] = PH24_2;
    }
    fft2048(zre, zim, wt, t);

#pragma unroll
    for (int u = 0; u < 8; ++u) {
        int s = t + u * 256;
        int j = (2048 - s) & 2047;
        Wt[base0 + s] = f2bf(zre[PD(j)] * (1.0f / 2048.0f));
        Wt[base1 + s] = f2bf(zim[PD(j)] * (1.0f / 2048.0f));
    }
}

// Layer-B fat kernel: q2 = Z2(ca,cb)=Wout[ca]*T[cb] (256, FIRST) +
// spectral (4096) + projV (1024) 4:1 + matvec2 tail (512, raw Wout).
__global__ __launch_bounds__(256) void fat_specv(const u16* __restrict__ Qt,
                                                 const u16* __restrict__ Kt,
                                                 u16* __restrict__ Wt,
                                                 const float* __restrict__ alpha,
                                                 const float2* __restrict__ gws,
                                                 const float* __restrict__ gph,
                                                 const u16* __restrict__ Av,
                                                 const u16* __restrict__ Ev,
                                                 const float* __restrict__ bvb,
                                                 void* __restrict__ Vt,
                                                 const u16* __restrict__ Xout,
                                                 const u16* __restrict__ Yt2,
                                                 void* __restrict__ Z2,
                                                 const float* __restrict__ Wout,
                                                 const float* __restrict__ bv1,
                                                 const float* __restrict__ bout,
                                                 float* __restrict__ bv2) {
    __shared__ __align__(16) char smem[32768];
    int bid = blockIdx.x;
    if (bid < 256) {
        gemm_body<512, 0, 16>(bid, (u16*)smem, (u16*)(smem + 16384),
                              Xout, Yt2, nullptr, Z2);
        return;
    }
    if (bid >= 5376) {
        mvW_body(bid - 5376, bv1, Wout, bout, bv2);
        return;
    }
    bid -= 256;
    if (bid % 5 == 4) {
        gemm_body<512, 2, 64>(bid / 5, (u16*)smem, (u16*)(smem + 16384),
                              Av, Ev, bvb, Vt);
    } else {
        int sbid = (bid / 5) * 4 + (bid % 5);
        spectral_body(sbid, (float*)smem, (float*)(smem + 8960),
                      (float2*)(smem + 17920), Qt, Kt, Wt, alpha, gws, gph);
    }
}

// ---------------------------------------------------------------------------
// fat_post: qcomb2 (Z2 -> Ecomb, 1024 blocks) + transpose_mul (4096 blocks).
// ---------------------------------------------------------------------------
__device__ __forceinline__ void qcomb2_body(int blk, const u16* __restrict__ Z2,
                                            u16* __restrict__ Ecomb) {
    int id = blk * 256 + threadIdx.x;       // < 262144
    int q = id >> 9, i = id & 511;
    float z[4][4];
#pragma unroll
    for (int ca = 0; ca < 4; ++ca)
#pragma unroll
        for (int cb = 0; cb < 4; ++cb)
            z[ca][cb] = bf2f(Z2[(size_t)(ca * 512 + q) * 2048 + cb * 512 + i]);
    float wc[4];
    wc[0] = z[0][0] - z[1][1] - z[2][2] - z[3][3];
    wc[1] = z[1][0] + z[0][1] + z[3][2] - z[2][3];
    wc[2] = z[2][0] + z[0][2] + z[1][3] - z[3][1];
    wc[3] = z[3][0] + z[0][3] + z[2][1] - z[1][2];
#pragma unroll
    for (int c = 0; c < 4; ++c) {
        u16x4 row;
#pragma unroll
        for (int cp = 0; cp < 4; ++cp) {
            int qmv; float qsv; hamilton(c, cp, qmv, qsv);
            row[cp] = f2bf(qsv * wc[qmv]);
        }
        *(u16x4*)&Ecomb[(size_t)(4 * q + c) * 2048 + 4 * i] = row;
    }
}

__device__ __forceinline__ void tmul_body(int blk, const u16* __restrict__ W,
                                          const u16* __restrict__ V,
                                          u16* __restrict__ out, u16* tile) {
    // tile: [64][70] u16
    const int b  = blk >> 10;
    const int rem = blk & 1023;
    const int c0 = (rem & 31) * 64, s0 = (rem >> 5) * 64;
    const int t  = threadIdx.x;
    const int g  = (t & 15) * 4;
    const int rb = t >> 4;
#pragma unroll
    for (int r = 0; r < 4; ++r) {
        int c = rb + 16 * r;
        size_t idx = ((size_t)b * 2048 + c0 + c) * 2048 + s0 + g;
        u16x4 wv = *(const u16x4*)&W[idx];
        u16x4 vv = *(const u16x4*)&V[idx];
#pragma unroll
        for (int j = 0; j < 4; ++j)
            tile[c * 70 + g + j] = f2bf(bf2f(wv[j]) * bf2f(vv[j]));
    }
    __syncthreads();
#pragma unroll
    for (int r = 0; r < 4; ++r) {
        int s = rb + 16 * r;
        u16x4 o;
#pragma unroll
        for (int j = 0; j < 4; ++j) o[j] = tile[(g + j) * 70 + s];
        *(u16x4*)&out[((size_t)b * 2048 + s0 + s) * 2048 + c0 + g] = o;
    }
}

__global__ __launch_bounds__(256) void fat_post(const u16* __restrict__ Z2,
                                                u16* __restrict__ Ecomb,
                                                const u16* __restrict__ W,
                                                const u16* __restrict__ V,
                                                u16* __restrict__ attn) {
    __shared__ u16 tile[64 * 70];
    int bid = blockIdx.x;
    if (bid < 1024) qcomb2_body(bid, Z2, Ecomb);
    else            tmul_body(bid - 1024, W, V, attn, tile);
}

// ---------------------------------------------------------------------------
extern "C" void kernel_launch(void* const* d_in, const int* in_sizes, int n_in,
                              void* d_out, int out_size, void* d_ws, size_t ws_size,
                              hipStream_t stream) {
    const float* query = (const float*)d_in[0];
    const float* key   = (const float*)d_in[1];
    const float* value = (const float*)d_in[2];
    const float* Wq    = (const float*)d_in[3];
    const float* bq    = (const float*)d_in[4];
    const float* Wk    = (const float*)d_in[5];
    const float* bk    = (const float*)d_in[6];
    const float* Wv    = (const float*)d_in[7];
    const float* bv    = (const float*)d_in[8];
    const float* alpha = (const float*)d_in[9];
    const float* Wint  = (const float*)d_in[10];
    const float* bint  = (const float*)d_in[11];
    const float* Wfin  = (const float*)d_in[12];
    const float* bfin  = (const float*)d_in[13];
    const float* Wout  = (const float*)d_in[14];
    const float* bout  = (const float*)d_in[15];

    char* ws = (char*)d_ws;
    size_t off = 0;
    auto alloc = [&](size_t bytes) -> void* {
        void* p = ws + off;
        off += (bytes + 255) & ~(size_t)255;
        return p;
    };
    u16* Eq    = (u16*)alloc((size_t)2048 * 512 * 2);
    u16* Ek    = (u16*)alloc((size_t)2048 * 512 * 2);
    u16* Ev    = (u16*)alloc((size_t)2048 * 512 * 2);
    u16* Xfin  = (u16*)alloc((size_t)2048 * 512 * 2);
    u16* Xout  = (u16*)alloc((size_t)2048 * 512 * 2);
    u16* YtInt = (u16*)alloc((size_t)2048 * 512 * 2);
    u16* Yt2   = (u16*)alloc((size_t)2048 * 512 * 2);
    u16* Z1    = (u16*)alloc((size_t)2048 * 2048 * 2);
    u16* Z2    = (u16*)alloc((size_t)2048 * 2048 * 2);
    u16* Ecomb = (u16*)alloc((size_t)2048 * 2048 * 2);
    u16* Qt    = (u16*)alloc((size_t)4 * 2048 * 2048 * 2);
    u16* Kt    = (u16*)alloc((size_t)4 * 2048 * 2048 * 2);
    u16* Vt    = (u16*)alloc((size_t)4 * 2048 * 2048 * 2);
    u16* attn  = (u16*)alloc((size_t)8192 * 2048 * 2);
    float2* gws = (float2*)alloc(292 * 8);
    float*  pht = (float*)alloc(1025 * 4);
    float*  bv1 = (float*)alloc(2048 * 4);
    float*  bv2 = (float*)alloc(2048 * 4);
    u16* Wt = Qt;   // spectral writes weights in place over Qt
    u16* Aq = attn;
    u16* Ak = attn + (size_t)8192 * 512;
    u16* Av = attn + (size_t)8192 * 1024;

    // fused prep: cvt x3, E<9> x3, Xfin, Xout, YtInt, tables
    fat_prep<<<23557, 256, 0, stream>>>(query, key, value, Aq,
                                        Wq, Wk, Wv, Eq, Ek, Ev,
                                        Wint, Wfin, Wout, Xfin, Xout, YtInt,
                                        gws, pht);

    // Layer A: q1 (first) + projQ + projK + matvec1 tail
    gemm_fatA<<<2816, 256, 0, stream>>>(Aq, Eq, bq, Qt, Ak, Ek, bk, Kt,
                                        Xfin, YtInt, Z1, Wfin, bint, bfin, bv1);

    // quaternion sign-combine 1: Z1 -> Yt2 (T transposed per comp)
    qcomb1<<<dim3(16, 16, 4), dim3(32, 8), 0, stream>>>(Z1, Yt2);

    // Layer B: q2 (first) + spectral (in-place over Qt) + projV + matvec2
    fat_specv<<<5888, 256, 0, stream>>>(Qt, Kt, Wt, alpha, gws, pht,
                                        Av, Ev, bv, Vt, Xout, Yt2, Z2,
                                        Wout, bv1, bout, bv2);

    // qcomb2 (Z2 -> Ecomb) + transpose_mul (attn = (W.*V)^T), one grid
    fat_post<<<5120, 256, 0, stream>>>(Z2, Ecomb, Wt, Vt, attn);

    // single fused trailing linear
    gemm2<2048, 1, 64><<<1024, 256, 0, stream>>>(attn, Ecomb, bv2, (float*)d_out);
}